// Round 2
// baseline (264.925 us; speedup 1.0000x reference)
//
#include <hip/hip_runtime.h>

#define B_ 64
#define S_ 200
#define H_ 256
#define A_ 16
#define M_ (B_*S_)
#define NEGV (-1000000000.0f)

typedef unsigned short ushortT;
typedef __attribute__((ext_vector_type(8))) short short8;
typedef __attribute__((ext_vector_type(4))) float f32x4;

__device__ __forceinline__ ushortT bf16u(float f) {
  unsigned int u = __builtin_bit_cast(unsigned int, f);
  unsigned int r = (u + 0x7fffu + ((u >> 16) & 1u)) >> 16;
  return (ushortT)r;
}
__device__ __forceinline__ float bf2f(ushortT u) {
  unsigned int v = ((unsigned int)u) << 16;
  return __builtin_bit_cast(float, v);
}

// ---------------- prep: bf16 conversions + weight transposes + gates/idx ----------------
__global__ __launch_bounds__(256) void prep_kernel(
    const float* __restrict__ item, const int* __restrict__ iseq,
    const int* __restrict__ tseq, const float* __restrict__ Wa1,
    const float* __restrict__ W_lin, const float* __restrict__ asp,
    const float* __restrict__ pos, const float* __restrict__ tdt,
    const float* __restrict__ tdn,
    ushortT* __restrict__ itemB, ushortT* __restrict__ tmaB,
    ushortT* __restrict__ Wa1T, ushortT* __restrict__ WlinT,
    float* __restrict__ gates_raw, float* __restrict__ idxf)
{
  const int blk = blockIdx.x;
  const int t = threadIdx.x;

  if (blk >= 800) {
    // ---- weight transpose: 32 blocks, 16 per weight, 64x64 tiles ----
    __shared__ float T[64*65];
    int wsel = (blk - 800) >> 4;
    int tile = (blk - 800) & 15;
    const float* W = wsel ? W_lin : Wa1;
    ushortT* WT = wsel ? WlinT : Wa1T;
    int tr = (tile >> 2) * 64, tc = (tile & 3) * 64;
    #pragma unroll
    for (int p = 0; p < 16; ++p) {
      int r = p*4 + (t >> 6);   // k-local
      int c = t & 63;           // n-local
      T[c*65 + r] = W[(tr + r)*H_ + tc + c];
    }
    __syncthreads();
    #pragma unroll
    for (int p = 0; p < 16; ++p) {
      int n = p*4 + (t >> 6);
      int k = t & 63;
      WT[(tc + n)*H_ + tr + k] = bf16u(T[n*65 + k]);
    }
    return;
  }

  __shared__ float aspl[16*260];
  __shared__ float gL[16*20];
  __shared__ int sL[16], ttL[16], tnL[16];

  const int m0 = blk * 16;
  if (t < 16) {
    int m = m0 + t;
    sL[t]  = m % S_;
    ttL[t] = tseq[2*m];
    tnL[t] = tseq[2*m+1];
  }
  // stage aspect embeddings (16 x 256)
  #pragma unroll
  for (int i = 0; i < 4; ++i) {
    int e = t + 256*i;
    int r = e >> 6, c = e & 63;
    *(float4*)&aspl[r*260 + 4*c] = *(const float4*)&asp[r*H_ + 4*c];
  }
  __syncthreads();

  // bf16 conversions (col = t)
  #pragma unroll 4
  for (int r = 0; r < 16; ++r) {
    int m = m0 + r;
    float iv = item[(size_t)m*H_ + t];
    float tv = iv + pos[sL[r]*H_ + t] + tdt[ttL[r]*H_ + t] + tdn[tnL[r]*H_ + t];
    itemB[(size_t)m*H_ + t] = bf16u(iv);
    tmaB[(size_t)m*H_ + t]  = bf16u(tv);
  }

  // gates (f32, exact-order like round 1) + argmax
  {
    int r = t >> 4, a = t & 15;
    int m = m0 + r;
    float g = 0.f;
    #pragma unroll 4
    for (int k4 = 0; k4 < 64; ++k4) {
      float4 xv = *(const float4*)&item[(size_t)m*H_ + 4*k4];
      float4 av = *(const float4*)&aspl[a*260 + 4*k4];
      g += xv.x*av.x + xv.y*av.y + xv.z*av.z + xv.w*av.w;
    }
    gL[r*20 + a] = g;
  }
  __syncthreads();
  if (t < 64) {
    int r = t >> 2, q = t & 3;
    float4 gv;
    gv.x = gL[r*20 + 4*q + 0]; gv.y = gL[r*20 + 4*q + 1];
    gv.z = gL[r*20 + 4*q + 2]; gv.w = gL[r*20 + 4*q + 3];
    *(float4*)&gates_raw[(m0+r)*A_ + 4*q] = gv;
  }
  if (t < 16) {
    float best = gL[t*20]; int bi = 0;
    #pragma unroll
    for (int a = 1; a < 16; ++a) {
      float v = gL[t*20 + a];
      if (v > best) { best = v; bi = a; }
    }
    idxf[m0 + t] = (float)bi;
  }
}

// ---------------- MFMA GEMM: both 12800x256x256 GEMMs (y = which) ----------------
// BM=64, BN=256(full), BK=32; 4 waves, each owns a 16x256 stripe (16 MFMA tiles).
__global__ __launch_bounds__(256) void gemm_kernel(
    const ushortT* __restrict__ tmaB, const ushortT* __restrict__ itemB,
    const ushortT* __restrict__ Wa1T, const ushortT* __restrict__ WlinT,
    const float* __restrict__ item, const int* __restrict__ iseq,
    const float* __restrict__ ba1, const float* __restrict__ Wa2,
    const float* __restrict__ ba2, const float* __restrict__ b_lin,
    const float* __restrict__ g_ln, const float* __restrict__ b_ln,
    float* __restrict__ w_out, float* __restrict__ moe_out)
{
  __shared__ ushortT Al[64*40];    // [row][k] padded stride 40
  __shared__ ushortT Bl[256*40];   // [n][k]  padded stride 40

  const int g = blockIdx.y;
  const ushortT* __restrict__ Ap  = g ? itemB : tmaB;
  const ushortT* __restrict__ WTp = g ? WlinT : Wa1T;

  const int t = threadIdx.x;
  const int m0 = blockIdx.x * 64;
  const int lane = t & 63, w = t >> 6;
  const int col = lane & 15;     // MFMA col / frag row
  const int rg  = lane >> 4;     // row-group, k-slot selector

  f32x4 acc[16];
  #pragma unroll
  for (int i = 0; i < 16; ++i) acc[i] = (f32x4){0.f,0.f,0.f,0.f};

  const int ar = t >> 2, akq = (t & 3) * 8;

  for (int k0 = 0; k0 < H_; k0 += 32) {
    __syncthreads();
    *(uint4*)&Al[ar*40 + akq] = *(const uint4*)&Ap[(size_t)(m0 + ar)*H_ + k0 + akq];
    #pragma unroll
    for (int i = 0; i < 4; ++i) {
      int n = i*64 + ar;
      *(uint4*)&Bl[n*40 + akq] = *(const uint4*)&WTp[(size_t)n*H_ + k0 + akq];
    }
    __syncthreads();
    short8 af = *(const short8*)&Al[(w*16 + col)*40 + rg*8];
    #pragma unroll
    for (int q = 0; q < 16; ++q) {
      short8 bf = *(const short8*)&Bl[(q*16 + col)*40 + rg*8];
      acc[q] = __builtin_amdgcn_mfma_f32_16x16x32_bf16(af, bf, acc[q], 0, 0, 0);
    }
  }

  if (g == 0) {
    // w = leaky(C + ba1) . Wa2 + ba2, pad -> NEG
    float bav[16], wav[16];
    #pragma unroll
    for (int q = 0; q < 16; ++q) {
      int n = q*16 + col;
      bav[q] = ba1[n]; wav[q] = Wa2[n];
    }
    float bb2 = ba2[0];
    #pragma unroll
    for (int j = 0; j < 4; ++j) {
      float p = 0.f;
      #pragma unroll
      for (int q = 0; q < 16; ++q) {
        float h = acc[q][j] + bav[q];
        h = (h >= 0.f) ? h : 0.01f*h;
        p += h * wav[q];
      }
      #pragma unroll
      for (int mk = 1; mk < 16; mk <<= 1) p += __shfl_xor(p, mk);
      if (col == 0) {
        int m = m0 + w*16 + rg*4 + j;
        w_out[m] = (iseq[m] == 0) ? NEGV : (p + bb2);
      }
    }
  } else {
    // moe = LN(tanh(C + b_lin) + item_f32)
    float blv[16], glv[16], bbv[16];
    #pragma unroll
    for (int q = 0; q < 16; ++q) {
      int n = q*16 + col;
      blv[q] = b_lin[n]; glv[q] = g_ln[n]; bbv[q] = b_ln[n];
    }
    #pragma unroll
    for (int j = 0; j < 4; ++j) {
      int m = m0 + w*16 + rg*4 + j;
      float v[16];
      float s1 = 0.f, s2 = 0.f;
      #pragma unroll
      for (int q = 0; q < 16; ++q) {
        float iv = item[(size_t)m*H_ + q*16 + col];
        float vv = tanhf(acc[q][j] + blv[q]) + iv;
        v[q] = vv; s1 += vv; s2 += vv*vv;
      }
      #pragma unroll
      for (int mk = 1; mk < 16; mk <<= 1) {
        s1 += __shfl_xor(s1, mk);
        s2 += __shfl_xor(s2, mk);
      }
      float mu  = s1 * (1.0f/H_);
      float var = s2 * (1.0f/H_) - mu*mu;
      float rs  = 1.0f / sqrtf(fmaxf(var, 0.f) + 1e-12f);
      #pragma unroll
      for (int q = 0; q < 16; ++q)
        moe_out[(size_t)m*H_ + q*16 + col] = (v[q] - mu)*rs*glv[q] + bbv[q];
    }
  }
}

// ---------------- Phase C (one block per batch) ----------------
__device__ __forceinline__ float blk_max(float v, float* red) {
  #pragma unroll
  for (int mk = 32; mk; mk >>= 1) v = fmaxf(v, __shfl_xor(v, mk));
  int t = threadIdx.x;
  if ((t & 63) == 0) red[t >> 6] = v;
  __syncthreads();
  if (t < 64) {
    float x = (t < 16) ? red[t] : -3.0e38f;
    #pragma unroll
    for (int mk = 8; mk; mk >>= 1) x = fmaxf(x, __shfl_xor(x, mk));
    if (t == 0) red[0] = x;
  }
  __syncthreads();
  float r = red[0];
  __syncthreads();
  return r;
}

__device__ __forceinline__ float blk_sum(float v, float* red) {
  #pragma unroll
  for (int mk = 32; mk; mk >>= 1) v += __shfl_xor(v, mk);
  int t = threadIdx.x;
  if ((t & 63) == 0) red[t >> 6] = v;
  __syncthreads();
  if (t < 64) {
    float x = (t < 16) ? red[t] : 0.f;
    #pragma unroll
    for (int mk = 8; mk; mk >>= 1) x += __shfl_xor(x, mk);
    if (t == 0) red[0] = x;
  }
  __syncthreads();
  float r = red[0];
  __syncthreads();
  return r;
}

__global__ __launch_bounds__(1024) void phaseC_kernel(
    const int* __restrict__ iseq, const float* __restrict__ w_in,
    const float* __restrict__ moe, const float* __restrict__ idxf,
    float* __restrict__ gates_rs,   // raw in -> softmax out (OUT1)
    float* __restrict__ cap_out,    // OUT0
    float* __restrict__ mask_out,   // OUT2
    float* __restrict__ aidx_out,   // OUT4
    float* __restrict__ act_out)    // OUT3 (activated)
{
  __shared__ float bij[S_*20];
  __shared__ float wgt[S_*20];
  __shared__ float capl[A_*260];
  __shared__ float tmaL[S_];
  __shared__ float red[16];
  __shared__ float maskf[A_];
  __shared__ int counts[A_], maxpos[A_];
  __shared__ int idxl[S_];
  __shared__ int padl[S_];

  const int t = threadIdx.x;
  const int b = blockIdx.x;
  const int base = b * S_;

  if (t < A_) { counts[t] = 0; maxpos[t] = -1; }
  float wv = -3.0e38f;
  if (t < S_) {
    int s = t;
    padl[s] = (iseq[base+s] == 0) ? 1 : 0;
    idxl[s] = (int)idxf[base+s];
    wv = w_in[base+s];
    #pragma unroll
    for (int q = 0; q < 4; ++q)
      *(float4*)&bij[s*20 + 4*q] = *(const float4*)&gates_rs[(base+s)*A_ + 4*q];
  }
  __syncthreads();

  if (t < S_ && !padl[t]) {
    atomicAdd(&counts[idxl[t]], 1);
    atomicMax(&maxpos[idxl[t]], t + 1);
  }
  // gates softmax -> overwrite OUT1
  if (t < S_) {
    int s = t;
    float row[16]; float mx = -3.0e38f;
    #pragma unroll
    for (int a = 0; a < 16; ++a) { row[a] = bij[s*20+a]; mx = fmaxf(mx, row[a]); }
    float sm = 0.f;
    #pragma unroll
    for (int a = 0; a < 16; ++a) { row[a] = expf(row[a] - mx); sm += row[a]; }
    float inv = 1.f / sm;
    #pragma unroll
    for (int q = 0; q < 4; ++q) {
      float4 o; o.x=row[4*q]*inv; o.y=row[4*q+1]*inv; o.z=row[4*q+2]*inv; o.w=row[4*q+3]*inv;
      *(float4*)&gates_rs[(base+s)*A_ + 4*q] = o;
    }
  }
  // tma = softmax(w)
  float mxw = blk_max(wv, red);
  float ev = (t < S_) ? expf(wv - mxw) : 0.f;
  float sw = blk_sum(ev, red);
  if (t < S_) tmaL[t] = ev / sw;
  __syncthreads();
  if (t < A_) {
    int c = counts[t];
    float mkv = (c == 0) ? 1.f : 0.f;
    maskf[t] = mkv;
    mask_out[b*A_ + t] = mkv;
    int mp = maxpos[t];
    aidx_out[b*A_ + t] = (mp > 0) ? (float)(mp - 1) : -1.f;
  }
  __syncthreads();

  for (int iter = 0; iter < 3; ++iter) {
    // step1: wgt = softmax_a(mask? NEG : bij) * (pad?0:tma)
    if (t < S_) {
      int s = t;
      float row[16]; float mx = -3.0e38f;
      #pragma unroll
      for (int a = 0; a < 16; ++a) {
        float v = bij[s*20+a];
        v = (maskf[a] > 0.5f) ? NEGV : v;
        row[a] = v; mx = fmaxf(mx, v);
      }
      float sm = 0.f;
      #pragma unroll
      for (int a = 0; a < 16; ++a) { row[a] = expf(row[a] - mx); sm += row[a]; }
      float sc = (padl[s] ? 0.f : tmaL[s]) / sm;
      #pragma unroll
      for (int q = 0; q < 4; ++q) {
        float4 o; o.x=row[4*q]*sc; o.y=row[4*q+1]*sc; o.z=row[4*q+2]*sc; o.w=row[4*q+3]*sc;
        *(float4*)&wgt[s*20 + 4*q] = o;
      }
    }
    __syncthreads();
    // step2: cap[a][h] = sum_s wgt[s][a] * moe[s][h]  (8-wide batched loads)
    {
      int h = t & 255, a0 = (t >> 8) << 2;
      float ac0=0.f, ac1=0.f, ac2=0.f, ac3=0.f;
      const float* mrow = &moe[(size_t)base*H_ + h];
      for (int s0 = 0; s0 < S_; s0 += 8) {
        float mv[8];
        #pragma unroll
        for (int j = 0; j < 8; ++j) mv[j] = mrow[(size_t)(s0+j)*H_];
        #pragma unroll
        for (int j = 0; j < 8; ++j) {
          float4 wv4 = *(const float4*)&wgt[(s0+j)*20 + a0];
          ac0 += wv4.x*mv[j]; ac1 += wv4.y*mv[j];
          ac2 += wv4.z*mv[j]; ac3 += wv4.w*mv[j];
        }
      }
      capl[(a0+0)*260 + h] = ac0;
      capl[(a0+1)*260 + h] = ac1;
      capl[(a0+2)*260 + h] = ac2;
      capl[(a0+3)*260 + h] = ac3;
    }
    __syncthreads();
    // step3: squash per aspect
    {
      int w = t >> 6, l = t & 63;
      float v = 0.f;
      #pragma unroll
      for (int q = 0; q < 4; ++q) { float c = capl[w*260 + l + 64*q]; v += c*c; }
      #pragma unroll
      for (int mk = 32; mk; mk >>= 1) v += __shfl_xor(v, mk);
      float sc = v / (1.f + v) / sqrtf(v + 1e-9f);
      #pragma unroll
      for (int q = 0; q < 4; ++q) capl[w*260 + l + 64*q] *= sc;
    }
    __syncthreads();
    // step4: bij[s][a] += moe[s].cap[a]  (dead on last iter)
    if (iter < 2) {
      int a = t & 15, srow = t >> 4;
      for (int so = 0; so < 4; ++so) {
        int s = so*64 + srow;
        if (s < S_) {
          const float* mp_ = &moe[(size_t)(base+s)*H_];
          float accd = 0.f;
          #pragma unroll
          for (int k4 = 0; k4 < 64; k4 += 8) {
            float4 mv[8];
            #pragma unroll
            for (int u = 0; u < 8; ++u) mv[u] = *(const float4*)&mp_[4*(k4+u)];
            #pragma unroll
            for (int u = 0; u < 8; ++u) {
              float4 cv = *(const float4*)&capl[a*260 + 4*(k4+u)];
              accd += mv[u].x*cv.x + mv[u].y*cv.y + mv[u].z*cv.z + mv[u].w*cv.w;
            }
          }
          bij[s*20 + a] += accd;
        }
      }
      __syncthreads();
    }
  }
  // write final cap
  #pragma unroll
  for (int q = 0; q < 4; ++q) {
    int e = t + 1024*q;
    int a = e >> 8, h = e & 255;
    cap_out[((size_t)b*A_ + a)*H_ + h] = capl[a*260 + h];
  }
  // activated[b,s,:] = cap[b, idx[b,s], :]
  {
    int h4 = t & 63;
    for (int s = t >> 6; s < S_; s += 16) {
      float4 v = *(const float4*)&capl[idxl[s]*260 + 4*h4];
      *(float4*)&act_out[((size_t)base + s)*H_ + 4*h4] = v;
    }
  }
}

extern "C" void kernel_launch(void* const* d_in, const int* in_sizes, int n_in,
                              void* d_out, int out_size, void* d_ws, size_t ws_size,
                              hipStream_t stream) {
  (void)in_sizes; (void)n_in; (void)out_size; (void)ws_size;
  const float* item  = (const float*)d_in[0];
  const int*   iseq  = (const int*)d_in[1];
  const int*   tseq  = (const int*)d_in[2];
  const float* W_lin = (const float*)d_in[3];
  const float* b_lin = (const float*)d_in[4];
  const float* asp   = (const float*)d_in[5];
  const float* pos   = (const float*)d_in[6];
  const float* tdt   = (const float*)d_in[7];
  const float* tdn   = (const float*)d_in[8];
  const float* Wa1   = (const float*)d_in[9];
  const float* ba1   = (const float*)d_in[10];
  const float* Wa2   = (const float*)d_in[11];
  const float* ba2   = (const float*)d_in[12];
  const float* g_ln  = (const float*)d_in[13];
  const float* b_ln  = (const float*)d_in[14];

  float* out    = (float*)d_out;
  float* cap_o  = out;                 // B*A*H     = 262144
  float* gate_o = out + 262144;        // B*S*A     = 204800
  float* mask_o = out + 466944;        // B*A       = 1024
  float* act_o  = out + 467968;        // B*S*H     = 3276800 (bf16 scratch, then activated)
  float* aidx_o = out + 3744768;       // B*A       = 1024
  float* idx_o  = out + 3745792;       // B*S       = 12800

  // scratch in d_ws: moe f32 (13.1 MB) | Wa1T bf16 | WlinT bf16 | w f32
  float*   moe_ws = (float*)d_ws;
  ushortT* Wa1T   = (ushortT*)((char*)d_ws + 13107200);
  ushortT* WlinT  = Wa1T + 65536;
  float*   w_ws   = (float*)((char*)d_ws + 13107200 + 262144);

  // bf16 activations live in the act_o region until phaseC overwrites it
  ushortT* itemB = (ushortT*)act_o;
  ushortT* tmaB  = itemB + (size_t)M_*H_;

  prep_kernel<<<832, 256, 0, stream>>>(item, iseq, tseq, Wa1, W_lin, asp,
      pos, tdt, tdn, itemB, tmaB, Wa1T, WlinT, gate_o, idx_o);
  gemm_kernel<<<dim3(M_/64, 2), 256, 0, stream>>>(tmaB, itemB, Wa1T, WlinT,
      item, iseq, ba1, Wa2, ba2, b_lin, g_ln, b_ln, w_ws, moe_ws);
  phaseC_kernel<<<B_, 1024, 0, stream>>>(iseq, w_ws, moe_ws, idx_o,
      gate_o, cap_o, mask_o, aidx_o, act_o);
}

// Round 3
// 112.343 us; speedup vs baseline: 2.3582x; 2.3582x over previous
//
#include <hip/hip_runtime.h>

#define B_ 64
#define S_ 200
#define H_ 256
#define A_ 16
#define M_ (B_*S_)
#define NEGV (-1000000000.0f)

typedef unsigned short ushortT;
typedef __attribute__((ext_vector_type(8))) short short8;
typedef __attribute__((ext_vector_type(4))) float f32x4;

__device__ __forceinline__ ushortT bf16u(float f) {
  unsigned int u = __builtin_bit_cast(unsigned int, f);
  unsigned int r = (u + 0x7fffu + ((u >> 16) & 1u)) >> 16;
  return (ushortT)r;
}
__device__ __forceinline__ float bf2f(ushortT u) {
  unsigned int v = ((unsigned int)u) << 16;
  return __builtin_bit_cast(float, v);
}

// ---------------- prep: bf16 conversions + weight transposes + gates/idx ----------------
__global__ __launch_bounds__(256) void prep_kernel(
    const float* __restrict__ item, const int* __restrict__ iseq,
    const int* __restrict__ tseq, const float* __restrict__ Wa1,
    const float* __restrict__ W_lin, const float* __restrict__ asp,
    const float* __restrict__ pos, const float* __restrict__ tdt,
    const float* __restrict__ tdn,
    ushortT* __restrict__ itemB, ushortT* __restrict__ tmaB,
    ushortT* __restrict__ Wa1T, ushortT* __restrict__ WlinT,
    float* __restrict__ gates_raw, float* __restrict__ idxf)
{
  const int blk = blockIdx.x;
  const int t = threadIdx.x;

  if (blk >= 800) {
    // ---- weight transpose: 32 blocks, 16 per weight, 64x64 tiles ----
    __shared__ float T[64*65];
    int wsel = (blk - 800) >> 4;
    int tile = (blk - 800) & 15;
    const float* W = wsel ? W_lin : Wa1;
    ushortT* WT = wsel ? WlinT : Wa1T;
    int tr = (tile >> 2) * 64, tc = (tile & 3) * 64;
    #pragma unroll
    for (int p = 0; p < 16; ++p) {
      int r = p*4 + (t >> 6);   // k-local
      int c = t & 63;           // n-local
      T[c*65 + r] = W[(tr + r)*H_ + tc + c];
    }
    __syncthreads();
    #pragma unroll
    for (int p = 0; p < 16; ++p) {
      int n = p*4 + (t >> 6);
      int k = t & 63;
      WT[(tc + n)*H_ + tr + k] = bf16u(T[n*65 + k]);
    }
    return;
  }

  __shared__ float aspl[16*260];
  __shared__ float gL[16*20];
  __shared__ int sL[16], ttL[16], tnL[16];

  const int m0 = blk * 16;
  if (t < 16) {
    int m = m0 + t;
    sL[t]  = m % S_;
    ttL[t] = tseq[2*m];
    tnL[t] = tseq[2*m+1];
  }
  // stage aspect embeddings (16 x 256)
  #pragma unroll
  for (int i = 0; i < 4; ++i) {
    int e = t + 256*i;
    int r = e >> 6, c = e & 63;
    *(float4*)&aspl[r*260 + 4*c] = *(const float4*)&asp[r*H_ + 4*c];
  }
  __syncthreads();

  // bf16 conversions (col = t)
  #pragma unroll 4
  for (int r = 0; r < 16; ++r) {
    int m = m0 + r;
    float iv = item[(size_t)m*H_ + t];
    float tv = iv + pos[sL[r]*H_ + t] + tdt[ttL[r]*H_ + t] + tdn[tnL[r]*H_ + t];
    itemB[(size_t)m*H_ + t] = bf16u(iv);
    tmaB[(size_t)m*H_ + t]  = bf16u(tv);
  }

  // gates (f32) + argmax
  {
    int r = t >> 4, a = t & 15;
    int m = m0 + r;
    float g = 0.f;
    #pragma unroll 4
    for (int k4 = 0; k4 < 64; ++k4) {
      float4 xv = *(const float4*)&item[(size_t)m*H_ + 4*k4];
      float4 av = *(const float4*)&aspl[a*260 + 4*k4];
      g += xv.x*av.x + xv.y*av.y + xv.z*av.z + xv.w*av.w;
    }
    gL[r*20 + a] = g;
  }
  __syncthreads();
  if (t < 64) {
    int r = t >> 2, q = t & 3;
    float4 gv;
    gv.x = gL[r*20 + 4*q + 0]; gv.y = gL[r*20 + 4*q + 1];
    gv.z = gL[r*20 + 4*q + 2]; gv.w = gL[r*20 + 4*q + 3];
    *(float4*)&gates_raw[(m0+r)*A_ + 4*q] = gv;
  }
  if (t < 16) {
    float best = gL[t*20]; int bi = 0;
    #pragma unroll
    for (int a = 1; a < 16; ++a) {
      float v = gL[t*20 + a];
      if (v > best) { best = v; bi = a; }
    }
    idxf[m0 + t] = (float)bi;
  }
}

// ---------------- MFMA GEMM: both 12800x256x256 GEMMs (y = which) ----------------
__global__ __launch_bounds__(256) void gemm_kernel(
    const ushortT* __restrict__ tmaB, const ushortT* __restrict__ itemB,
    const ushortT* __restrict__ Wa1T, const ushortT* __restrict__ WlinT,
    const float* __restrict__ item, const int* __restrict__ iseq,
    const float* __restrict__ ba1, const float* __restrict__ Wa2,
    const float* __restrict__ ba2, const float* __restrict__ b_lin,
    const float* __restrict__ g_ln, const float* __restrict__ b_ln,
    float* __restrict__ w_out, ushortT* __restrict__ moe_outB)
{
  __shared__ ushortT Al[64*40];    // [row][k] padded stride 40
  __shared__ ushortT Bl[256*40];   // [n][k]  padded stride 40

  const int g = blockIdx.y;
  const ushortT* __restrict__ Ap  = g ? itemB : tmaB;
  const ushortT* __restrict__ WTp = g ? WlinT : Wa1T;

  const int t = threadIdx.x;
  const int m0 = blockIdx.x * 64;
  const int lane = t & 63, w = t >> 6;
  const int col = lane & 15;     // MFMA col
  const int rg  = lane >> 4;     // row-group / k-slot

  f32x4 acc[16];
  #pragma unroll
  for (int i = 0; i < 16; ++i) acc[i] = (f32x4){0.f,0.f,0.f,0.f};

  const int ar = t >> 2, akq = (t & 3) * 8;

  for (int k0 = 0; k0 < H_; k0 += 32) {
    __syncthreads();
    *(uint4*)&Al[ar*40 + akq] = *(const uint4*)&Ap[(size_t)(m0 + ar)*H_ + k0 + akq];
    #pragma unroll
    for (int i = 0; i < 4; ++i) {
      int n = i*64 + ar;
      *(uint4*)&Bl[n*40 + akq] = *(const uint4*)&WTp[(size_t)n*H_ + k0 + akq];
    }
    __syncthreads();
    short8 af = *(const short8*)&Al[(w*16 + col)*40 + rg*8];
    #pragma unroll
    for (int q = 0; q < 16; ++q) {
      short8 bf = *(const short8*)&Bl[(q*16 + col)*40 + rg*8];
      acc[q] = __builtin_amdgcn_mfma_f32_16x16x32_bf16(af, bf, acc[q], 0, 0, 0);
    }
  }

  if (g == 0) {
    float bav[16], wav[16];
    #pragma unroll
    for (int q = 0; q < 16; ++q) {
      int n = q*16 + col;
      bav[q] = ba1[n]; wav[q] = Wa2[n];
    }
    float bb2 = ba2[0];
    #pragma unroll
    for (int j = 0; j < 4; ++j) {
      float p = 0.f;
      #pragma unroll
      for (int q = 0; q < 16; ++q) {
        float h = acc[q][j] + bav[q];
        h = (h >= 0.f) ? h : 0.01f*h;
        p += h * wav[q];
      }
      #pragma unroll
      for (int mk = 1; mk < 16; mk <<= 1) p += __shfl_xor(p, mk);
      if (col == 0) {
        int m = m0 + w*16 + rg*4 + j;
        w_out[m] = (iseq[m] == 0) ? NEGV : (p + bb2);
      }
    }
  } else {
    float blv[16], glv[16], bbv[16];
    #pragma unroll
    for (int q = 0; q < 16; ++q) {
      int n = q*16 + col;
      blv[q] = b_lin[n]; glv[q] = g_ln[n]; bbv[q] = b_ln[n];
    }
    #pragma unroll
    for (int j = 0; j < 4; ++j) {
      int m = m0 + w*16 + rg*4 + j;
      float v[16];
      float s1 = 0.f, s2 = 0.f;
      #pragma unroll
      for (int q = 0; q < 16; ++q) {
        float iv = item[(size_t)m*H_ + q*16 + col];
        float vv = tanhf(acc[q][j] + blv[q]) + iv;
        v[q] = vv; s1 += vv; s2 += vv*vv;
      }
      #pragma unroll
      for (int mk = 1; mk < 16; mk <<= 1) {
        s1 += __shfl_xor(s1, mk);
        s2 += __shfl_xor(s2, mk);
      }
      float mu  = s1 * (1.0f/H_);
      float var = s2 * (1.0f/H_) - mu*mu;
      float rs  = 1.0f / sqrtf(fmaxf(var, 0.f) + 1e-12f);
      #pragma unroll
      for (int q = 0; q < 16; ++q)
        moe_outB[(size_t)m*H_ + q*16 + col] = bf16u((v[q] - mu)*rs*glv[q] + bbv[q]);
    }
  }
}

// ---------------- Phase C (one block per batch; moe staged in LDS bf16) ----------------
__device__ __forceinline__ float blk_max(float v, float* red) {
  #pragma unroll
  for (int mk = 32; mk; mk >>= 1) v = fmaxf(v, __shfl_xor(v, mk));
  int t = threadIdx.x;
  if ((t & 63) == 0) red[t >> 6] = v;
  __syncthreads();
  if (t < 64) {
    float x = (t < 16) ? red[t] : -3.0e38f;
    #pragma unroll
    for (int mk = 8; mk; mk >>= 1) x = fmaxf(x, __shfl_xor(x, mk));
    if (t == 0) red[0] = x;
  }
  __syncthreads();
  float r = red[0];
  __syncthreads();
  return r;
}

__device__ __forceinline__ float blk_sum(float v, float* red) {
  #pragma unroll
  for (int mk = 32; mk; mk >>= 1) v += __shfl_xor(v, mk);
  int t = threadIdx.x;
  if ((t & 63) == 0) red[t >> 6] = v;
  __syncthreads();
  if (t < 64) {
    float x = (t < 16) ? red[t] : 0.f;
    #pragma unroll
    for (int mk = 8; mk; mk >>= 1) x += __shfl_xor(x, mk);
    if (t == 0) red[0] = x;
  }
  __syncthreads();
  float r = red[0];
  __syncthreads();
  return r;
}

#define MST 264   // moe LDS stride (bf16 elems): 528B rows, 16B aligned, 4-bank skew

__global__ __launch_bounds__(1024) void phaseC_kernel(
    const int* __restrict__ iseq, const float* __restrict__ w_in,
    const ushortT* __restrict__ moeB, const float* __restrict__ idxf,
    float* __restrict__ gates_rs,   // raw in -> softmax out (OUT1)
    float* __restrict__ cap_out,    // OUT0
    float* __restrict__ mask_out,   // OUT2
    float* __restrict__ aidx_out,   // OUT4
    float* __restrict__ act_out)    // OUT3 (activated)
{
  __shared__ ushortT moeL[S_*MST];  // 105600 B
  __shared__ float bij[S_*20];      // 16000 B
  __shared__ float wgt[S_*20];      // 16000 B (tail reused as capB bf16 during step4)
  __shared__ float capl[A_*260];    // 16640 B
  __shared__ float tmaL[S_];
  __shared__ float red[16];
  __shared__ float maskf[A_];
  __shared__ int counts[A_], maxpos[A_];
  __shared__ int idxl[S_];
  __shared__ int padl[S_];

  const int t = threadIdx.x;
  const int b = blockIdx.x;
  const int base = b * S_;

  // ---- stage moe (bf16) into LDS: 200 rows x 512B = 6400 uint4 ----
  #pragma unroll
  for (int u = 0; u < 7; ++u) {
    int e = t + 1024*u;
    if (e < 6400) {
      int r = e >> 5, c = (e & 31) << 3;
      *(uint4*)&moeL[r*MST + c] = *(const uint4*)&moeB[((size_t)(base + r))*H_ + c];
    }
  }

  if (t < A_) { counts[t] = 0; maxpos[t] = -1; }
  float wv = -3.0e38f;
  if (t < S_) {
    int s = t;
    padl[s] = (iseq[base+s] == 0) ? 1 : 0;
    idxl[s] = (int)idxf[base+s];
    wv = w_in[base+s];
    #pragma unroll
    for (int q = 0; q < 4; ++q)
      *(float4*)&bij[s*20 + 4*q] = *(const float4*)&gates_rs[(base+s)*A_ + 4*q];
  }
  __syncthreads();

  if (t < S_ && !padl[t]) {
    atomicAdd(&counts[idxl[t]], 1);
    atomicMax(&maxpos[idxl[t]], t + 1);
  }
  // gates softmax -> overwrite OUT1
  if (t < S_) {
    int s = t;
    float row[16]; float mx = -3.0e38f;
    #pragma unroll
    for (int a = 0; a < 16; ++a) { row[a] = bij[s*20+a]; mx = fmaxf(mx, row[a]); }
    float sm = 0.f;
    #pragma unroll
    for (int a = 0; a < 16; ++a) { row[a] = expf(row[a] - mx); sm += row[a]; }
    float inv = 1.f / sm;
    #pragma unroll
    for (int q = 0; q < 4; ++q) {
      float4 o; o.x=row[4*q]*inv; o.y=row[4*q+1]*inv; o.z=row[4*q+2]*inv; o.w=row[4*q+3]*inv;
      *(float4*)&gates_rs[(base+s)*A_ + 4*q] = o;
    }
  }
  // tma = softmax(w)
  float mxw = blk_max(wv, red);
  float ev = (t < S_) ? expf(wv - mxw) : 0.f;
  float sw = blk_sum(ev, red);
  if (t < S_) tmaL[t] = ev / sw;
  __syncthreads();
  if (t < A_) {
    int c = counts[t];
    float mkv = (c == 0) ? 1.f : 0.f;
    maskf[t] = mkv;
    mask_out[b*A_ + t] = mkv;
    int mp = maxpos[t];
    aidx_out[b*A_ + t] = (mp > 0) ? (float)(mp - 1) : -1.f;
  }
  __syncthreads();

  for (int iter = 0; iter < 3; ++iter) {
    // step1: wgt = softmax_a(mask? NEG : bij) * (pad?0:tma)
    if (t < S_) {
      int s = t;
      float row[16]; float mx = -3.0e38f;
      #pragma unroll
      for (int a = 0; a < 16; ++a) {
        float v = bij[s*20+a];
        v = (maskf[a] > 0.5f) ? NEGV : v;
        row[a] = v; mx = fmaxf(mx, v);
      }
      float sm = 0.f;
      #pragma unroll
      for (int a = 0; a < 16; ++a) { row[a] = expf(row[a] - mx); sm += row[a]; }
      float sc = (padl[s] ? 0.f : tmaL[s]) / sm;
      #pragma unroll
      for (int q = 0; q < 4; ++q) {
        float4 o; o.x=row[4*q]*sc; o.y=row[4*q+1]*sc; o.z=row[4*q+2]*sc; o.w=row[4*q+3]*sc;
        *(float4*)&wgt[s*20 + 4*q] = o;
      }
    }
    __syncthreads();
    // step2: cap[a][h] = sum_s wgt[s][a] * moe[s][h]  — all from LDS
    {
      int h = t & 255, a0 = (t >> 8) << 2;
      float ac0=0.f, ac1=0.f, ac2=0.f, ac3=0.f;
      #pragma unroll 8
      for (int s = 0; s < S_; ++s) {
        float mv = bf2f(moeL[s*MST + h]);
        float4 wv4 = *(const float4*)&wgt[s*20 + a0];
        ac0 += wv4.x*mv; ac1 += wv4.y*mv;
        ac2 += wv4.z*mv; ac3 += wv4.w*mv;
      }
      capl[(a0+0)*260 + h] = ac0;
      capl[(a0+1)*260 + h] = ac1;
      capl[(a0+2)*260 + h] = ac2;
      capl[(a0+3)*260 + h] = ac3;
    }
    __syncthreads();
    // step3: squash per aspect; also emit bf16 copy of cap into wgt-region (capB)
    {
      int w = t >> 6, l = t & 63;
      float v = 0.f;
      #pragma unroll
      for (int q = 0; q < 4; ++q) { float c = capl[w*260 + l + 64*q]; v += c*c; }
      #pragma unroll
      for (int mk = 32; mk; mk >>= 1) v += __shfl_xor(v, mk);
      float sc = v / (1.f + v) / sqrtf(v + 1e-9f);
      ushortT* capB = (ushortT*)wgt;
      #pragma unroll
      for (int q = 0; q < 4; ++q) {
        float cv = capl[w*260 + l + 64*q] * sc;
        capl[w*260 + l + 64*q] = cv;
        capB[w*MST + l + 64*q] = bf16u(cv);
      }
    }
    __syncthreads();
    // step4: bij[s][a] += moe[s].cap[a]  (bf16 dots from LDS; dead on last iter)
    if (iter < 2) {
      if (t < 800) {
        int s = t >> 2, a0 = (t & 3) << 2;
        const ushortT* capB = (const ushortT*)wgt;
        float ac[4] = {0.f, 0.f, 0.f, 0.f};
        #pragma unroll 4
        for (int c = 0; c < 32; ++c) {
          short8 mv8 = *(const short8*)&moeL[s*MST + c*8];
          float mf[8];
          #pragma unroll
          for (int j = 0; j < 8; ++j) mf[j] = bf2f((ushortT)mv8[j]);
          #pragma unroll
          for (int a = 0; a < 4; ++a) {
            short8 cv8 = *(const short8*)&capB[(a0+a)*MST + c*8];
            #pragma unroll
            for (int j = 0; j < 8; ++j)
              ac[a] += mf[j] * bf2f((ushortT)cv8[j]);
          }
        }
        #pragma unroll
        for (int a = 0; a < 4; ++a) bij[s*20 + a0 + a] += ac[a];
      }
      __syncthreads();
    }
  }
  // write final cap
  #pragma unroll
  for (int q = 0; q < 4; ++q) {
    int e = t + 1024*q;
    int a = e >> 8, h = e & 255;
    cap_out[((size_t)b*A_ + a)*H_ + h] = capl[a*260 + h];
  }
  // activated[b,s,:] = cap[b, idx[b,s], :]
  {
    int h4 = t & 63;
    for (int s = t >> 6; s < S_; s += 16) {
      float4 v = *(const float4*)&capl[idxl[s]*260 + 4*h4];
      *(float4*)&act_out[((size_t)base + s)*H_ + 4*h4] = v;
    }
  }
}

extern "C" void kernel_launch(void* const* d_in, const int* in_sizes, int n_in,
                              void* d_out, int out_size, void* d_ws, size_t ws_size,
                              hipStream_t stream) {
  (void)in_sizes; (void)n_in; (void)out_size; (void)ws_size;
  const float* item  = (const float*)d_in[0];
  const int*   iseq  = (const int*)d_in[1];
  const int*   tseq  = (const int*)d_in[2];
  const float* W_lin = (const float*)d_in[3];
  const float* b_lin = (const float*)d_in[4];
  const float* asp   = (const float*)d_in[5];
  const float* pos   = (const float*)d_in[6];
  const float* tdt   = (const float*)d_in[7];
  const float* tdn   = (const float*)d_in[8];
  const float* Wa1   = (const float*)d_in[9];
  const float* ba1   = (const float*)d_in[10];
  const float* Wa2   = (const float*)d_in[11];
  const float* ba2   = (const float*)d_in[12];
  const float* g_ln  = (const float*)d_in[13];
  const float* b_ln  = (const float*)d_in[14];

  float* out    = (float*)d_out;
  float* cap_o  = out;                 // B*A*H     = 262144
  float* gate_o = out + 262144;        // B*S*A     = 204800
  float* mask_o = out + 466944;        // B*A       = 1024
  float* act_o  = out + 467968;        // B*S*H     = 3276800 (bf16 scratch, then activated)
  float* aidx_o = out + 3744768;       // B*A       = 1024
  float* idx_o  = out + 3745792;       // B*S       = 12800

  // scratch in d_ws: moeB bf16 (6.55MB) | Wa1T bf16 | WlinT bf16 | w f32
  ushortT* moeB  = (ushortT*)d_ws;
  ushortT* Wa1T  = (ushortT*)((char*)d_ws + 6553600);
  ushortT* WlinT = Wa1T + 65536;
  float*   w_ws  = (float*)((char*)d_ws + 6553600 + 262144);

  // bf16 activations live in the act_o region until phaseC overwrites it
  ushortT* itemB = (ushortT*)act_o;
  ushortT* tmaB  = itemB + (size_t)M_*H_;

  prep_kernel<<<832, 256, 0, stream>>>(item, iseq, tseq, Wa1, W_lin, asp,
      pos, tdt, tdn, itemB, tmaB, Wa1T, WlinT, gate_o, idx_o);
  gemm_kernel<<<dim3(M_/64, 2), 256, 0, stream>>>(tmaB, itemB, Wa1T, WlinT,
      item, iseq, ba1, Wa2, ba2, b_lin, g_ln, b_ln, w_ws, moeB);
  phaseC_kernel<<<B_, 1024, 0, stream>>>(iseq, w_ws, moeB, idx_o,
      gate_o, cap_o, mask_o, aidx_o, act_o);
}

// Round 4
// 60.989 us; speedup vs baseline: 4.3438x; 1.8420x over previous
//
#include <hip/hip_runtime.h>

#define B_ 64
#define S_ 200
#define H_ 256
#define A_ 16
#define M_ (B_*S_)
#define NEGV (-1000000000.0f)

typedef unsigned short ushortT;
typedef __attribute__((ext_vector_type(8))) short short8;
typedef __attribute__((ext_vector_type(4))) float f32x4;

__device__ __forceinline__ ushortT bf16u(float f) {
  unsigned int u = __builtin_bit_cast(unsigned int, f);
  unsigned int r = (u + 0x7fffu + ((u >> 16) & 1u)) >> 16;
  return (ushortT)r;
}
__device__ __forceinline__ float bf2f(ushortT u) {
  unsigned int v = ((unsigned int)u) << 16;
  return __builtin_bit_cast(float, v);
}

// ---------------- prep: bf16 conversions + weight transposes + gates/idx ----------------
__global__ __launch_bounds__(256) void prep_kernel(
    const float* __restrict__ item, const int* __restrict__ iseq,
    const int* __restrict__ tseq, const float* __restrict__ Wa1,
    const float* __restrict__ W_lin, const float* __restrict__ asp,
    const float* __restrict__ pos, const float* __restrict__ tdt,
    const float* __restrict__ tdn,
    ushortT* __restrict__ itemB, ushortT* __restrict__ tmaB,
    ushortT* __restrict__ Wa1T, ushortT* __restrict__ WlinT,
    float* __restrict__ gates_raw, float* __restrict__ idxf)
{
  const int blk = blockIdx.x;
  const int t = threadIdx.x;

  if (blk >= 800) {
    __shared__ float T[64*65];
    int wsel = (blk - 800) >> 4;
    int tile = (blk - 800) & 15;
    const float* W = wsel ? W_lin : Wa1;
    ushortT* WT = wsel ? WlinT : Wa1T;
    int tr = (tile >> 2) * 64, tc = (tile & 3) * 64;
    #pragma unroll
    for (int p = 0; p < 16; ++p) {
      int r = p*4 + (t >> 6);
      int c = t & 63;
      T[c*65 + r] = W[(tr + r)*H_ + tc + c];
    }
    __syncthreads();
    #pragma unroll
    for (int p = 0; p < 16; ++p) {
      int n = p*4 + (t >> 6);
      int k = t & 63;
      WT[(tc + n)*H_ + tr + k] = bf16u(T[n*65 + k]);
    }
    return;
  }

  __shared__ float aspl[16*260];
  __shared__ float gL[16*20];
  __shared__ int sL[16], ttL[16], tnL[16];

  const int m0 = blk * 16;
  if (t < 16) {
    int m = m0 + t;
    sL[t]  = m % S_;
    ttL[t] = tseq[2*m];
    tnL[t] = tseq[2*m+1];
  }
  #pragma unroll
  for (int i = 0; i < 4; ++i) {
    int e = t + 256*i;
    int r = e >> 6, c = e & 63;
    *(float4*)&aspl[r*260 + 4*c] = *(const float4*)&asp[r*H_ + 4*c];
  }
  __syncthreads();

  #pragma unroll 4
  for (int r = 0; r < 16; ++r) {
    int m = m0 + r;
    float iv = item[(size_t)m*H_ + t];
    float tv = iv + pos[sL[r]*H_ + t] + tdt[ttL[r]*H_ + t] + tdn[tnL[r]*H_ + t];
    itemB[(size_t)m*H_ + t] = bf16u(iv);
    tmaB[(size_t)m*H_ + t]  = bf16u(tv);
  }

  {
    int r = t >> 4, a = t & 15;
    int m = m0 + r;
    float g = 0.f;
    #pragma unroll 4
    for (int k4 = 0; k4 < 64; ++k4) {
      float4 xv = *(const float4*)&item[(size_t)m*H_ + 4*k4];
      float4 av = *(const float4*)&aspl[a*260 + 4*k4];
      g += xv.x*av.x + xv.y*av.y + xv.z*av.z + xv.w*av.w;
    }
    gL[r*20 + a] = g;
  }
  __syncthreads();
  if (t < 64) {
    int r = t >> 2, q = t & 3;
    float4 gv;
    gv.x = gL[r*20 + 4*q + 0]; gv.y = gL[r*20 + 4*q + 1];
    gv.z = gL[r*20 + 4*q + 2]; gv.w = gL[r*20 + 4*q + 3];
    *(float4*)&gates_raw[(m0+r)*A_ + 4*q] = gv;
  }
  if (t < 16) {
    float best = gL[t*20]; int bi = 0;
    #pragma unroll
    for (int a = 1; a < 16; ++a) {
      float v = gL[t*20 + a];
      if (v > best) { best = v; bi = a; }
    }
    idxf[m0 + t] = (float)bi;
  }
}

// ---------------- MFMA GEMM: both 12800x256x256 GEMMs (y = which) ----------------
__global__ __launch_bounds__(256) void gemm_kernel(
    const ushortT* __restrict__ tmaB, const ushortT* __restrict__ itemB,
    const ushortT* __restrict__ Wa1T, const ushortT* __restrict__ WlinT,
    const float* __restrict__ item, const int* __restrict__ iseq,
    const float* __restrict__ ba1, const float* __restrict__ Wa2,
    const float* __restrict__ ba2, const float* __restrict__ b_lin,
    const float* __restrict__ g_ln, const float* __restrict__ b_ln,
    float* __restrict__ w_out, ushortT* __restrict__ moe_outB)
{
  __shared__ ushortT Al[64*40];
  __shared__ ushortT Bl[256*40];

  const int g = blockIdx.y;
  const ushortT* __restrict__ Ap  = g ? itemB : tmaB;
  const ushortT* __restrict__ WTp = g ? WlinT : Wa1T;

  const int t = threadIdx.x;
  const int m0 = blockIdx.x * 64;
  const int lane = t & 63, w = t >> 6;
  const int col = lane & 15;
  const int rg  = lane >> 4;

  f32x4 acc[16];
  #pragma unroll
  for (int i = 0; i < 16; ++i) acc[i] = (f32x4){0.f,0.f,0.f,0.f};

  const int ar = t >> 2, akq = (t & 3) * 8;

  for (int k0 = 0; k0 < H_; k0 += 32) {
    __syncthreads();
    *(uint4*)&Al[ar*40 + akq] = *(const uint4*)&Ap[(size_t)(m0 + ar)*H_ + k0 + akq];
    #pragma unroll
    for (int i = 0; i < 4; ++i) {
      int n = i*64 + ar;
      *(uint4*)&Bl[n*40 + akq] = *(const uint4*)&WTp[(size_t)n*H_ + k0 + akq];
    }
    __syncthreads();
    short8 af = *(const short8*)&Al[(w*16 + col)*40 + rg*8];
    #pragma unroll
    for (int q = 0; q < 16; ++q) {
      short8 bf = *(const short8*)&Bl[(q*16 + col)*40 + rg*8];
      acc[q] = __builtin_amdgcn_mfma_f32_16x16x32_bf16(af, bf, acc[q], 0, 0, 0);
    }
  }

  if (g == 0) {
    float bav[16], wav[16];
    #pragma unroll
    for (int q = 0; q < 16; ++q) {
      int n = q*16 + col;
      bav[q] = ba1[n]; wav[q] = Wa2[n];
    }
    float bb2 = ba2[0];
    #pragma unroll
    for (int j = 0; j < 4; ++j) {
      float p = 0.f;
      #pragma unroll
      for (int q = 0; q < 16; ++q) {
        float h = acc[q][j] + bav[q];
        h = (h >= 0.f) ? h : 0.01f*h;
        p += h * wav[q];
      }
      #pragma unroll
      for (int mk = 1; mk < 16; mk <<= 1) p += __shfl_xor(p, mk);
      if (col == 0) {
        int m = m0 + w*16 + rg*4 + j;
        w_out[m] = (iseq[m] == 0) ? NEGV : (p + bb2);
      }
    }
  } else {
    float blv[16], glv[16], bbv[16];
    #pragma unroll
    for (int q = 0; q < 16; ++q) {
      int n = q*16 + col;
      blv[q] = b_lin[n]; glv[q] = g_ln[n]; bbv[q] = b_ln[n];
    }
    #pragma unroll
    for (int j = 0; j < 4; ++j) {
      int m = m0 + w*16 + rg*4 + j;
      float v[16];
      float s1 = 0.f, s2 = 0.f;
      #pragma unroll
      for (int q = 0; q < 16; ++q) {
        float iv = item[(size_t)m*H_ + q*16 + col];
        float vv = tanhf(acc[q][j] + blv[q]) + iv;
        v[q] = vv; s1 += vv; s2 += vv*vv;
      }
      #pragma unroll
      for (int mk = 1; mk < 16; mk <<= 1) {
        s1 += __shfl_xor(s1, mk);
        s2 += __shfl_xor(s2, mk);
      }
      float mu  = s1 * (1.0f/H_);
      float var = s2 * (1.0f/H_) - mu*mu;
      float rs  = 1.0f / sqrtf(fmaxf(var, 0.f) + 1e-12f);
      #pragma unroll
      for (int q = 0; q < 16; ++q)
        moe_outB[(size_t)m*H_ + q*16 + col] = bf16u((v[q] - mu)*rs*glv[q] + bbv[q]);
    }
  }
}

// ---------------- Phase C: MFMA routing (one block per batch) ----------------
__device__ __forceinline__ float blk_max(float v, float* red) {
  #pragma unroll
  for (int mk = 32; mk; mk >>= 1) v = fmaxf(v, __shfl_xor(v, mk));
  int t = threadIdx.x;
  if ((t & 63) == 0) red[t >> 6] = v;
  __syncthreads();
  if (t < 64) {
    float x = (t < 16) ? red[t] : -3.0e38f;
    #pragma unroll
    for (int mk = 8; mk; mk >>= 1) x = fmaxf(x, __shfl_xor(x, mk));
    if (t == 0) red[0] = x;
  }
  __syncthreads();
  float r = red[0];
  __syncthreads();
  return r;
}

__device__ __forceinline__ float blk_sum(float v, float* red) {
  #pragma unroll
  for (int mk = 32; mk; mk >>= 1) v += __shfl_xor(v, mk);
  int t = threadIdx.x;
  if ((t & 63) == 0) red[t >> 6] = v;
  __syncthreads();
  if (t < 64) {
    float x = (t < 16) ? red[t] : 0.f;
    #pragma unroll
    for (int mk = 8; mk; mk >>= 1) x += __shfl_xor(x, mk);
    if (t == 0) red[0] = x;
  }
  __syncthreads();
  float r = red[0];
  __syncthreads();
  return r;
}

// moeTr layout: [ht=16][ks=7][bp=8][sr=4][hc=16] bf16, where for s:
//   ks=s/32, s4l=(s/4)%8, bp = even s4l -> s4l/2, odd -> 4+s4l/2, sr=s%4.
// Serves: step2 A-operand (k=s) via ds_read_b64_tr_b16 (linear vaddr=base+lane*8),
//         step4 A-operand (k=h) via natural ds_read_b128.
#define WGSTR 232   // wgtT stride (bf16), s padded to 224 + bank skew
#define CBSTR 260   // capB stride (bf16)
#define CLSTR 252   // capl stride (f32), 16B-aligned rows

__global__ __launch_bounds__(1024) void phaseC_kernel(
    const int* __restrict__ iseq, const float* __restrict__ w_in,
    const ushortT* __restrict__ moeB, const float* __restrict__ idxf,
    float* __restrict__ gates_rs,   // raw in -> softmax out (OUT1)
    float* __restrict__ cap_out,    // OUT0
    float* __restrict__ mask_out,   // OUT2
    float* __restrict__ aidx_out,   // OUT4
    float* __restrict__ act_out)    // OUT3 (activated)
{
  __shared__ ushortT moeTr[57344];  // 114688 B
  __shared__ ushortT wgtT[16*WGSTR];// 7424 B
  __shared__ ushortT capB[16*CBSTR];// 8320 B
  __shared__ float bij[4032];       // 16128 B; capl f32 [16][252] aliases after last bij read
  __shared__ float n2p[16*17];
  __shared__ float n2s[16];
  __shared__ float tmaL[S_];
  __shared__ float red[16];
  __shared__ float maskf[A_];
  __shared__ int counts[A_], maxpos[A_];
  __shared__ int idxl[S_];
  __shared__ int padl[S_];

  const int t = threadIdx.x;
  const int b = blockIdx.x;
  const int base = b * S_;
  const int lane = t & 63, w = t >> 6;
  const int la = lane & 15, lg = lane >> 4;

  // ---- stage moe (bf16) into permuted LDS layout; zero s-tail [200,224) ----
  #pragma unroll
  for (int u = 0; u < 4; ++u) {
    int e = t + 1024*u;               // e = s*16 + ht  (coalesced global reads)
    if (e < 3584) {
      int ht = e & 15, s = e >> 4;
      int ks = s >> 5, s4l = (s >> 2) & 7, sr = s & 3;
      int bp = (s4l & 1) ? 4 + (s4l >> 1) : (s4l >> 1);
      int li = ((ht*7 + ks)*8 + bp)*64 + sr*16;
      if (s < S_) {
        const ushortT* gp = &moeB[((size_t)(base + s))*H_ + ht*16];
        *(uint4*)&moeTr[li]     = *(const uint4*)gp;
        *(uint4*)&moeTr[li + 8] = *(const uint4*)(gp + 8);
      } else {
        uint4 z = {0,0,0,0};
        *(uint4*)&moeTr[li] = z; *(uint4*)&moeTr[li + 8] = z;
      }
    }
  }
  // zero wgtT s-tail [200,232)
  if (t < 512) {
    int a = t >> 5, s = 200 + (t & 31);
    wgtT[a*WGSTR + s] = 0;
  }

  if (t < A_) { counts[t] = 0; maxpos[t] = -1; }
  float wv = -3.0e38f;
  if (t < S_) {
    int s = t;
    padl[s] = (iseq[base+s] == 0) ? 1 : 0;
    idxl[s] = (int)idxf[base+s];
    wv = w_in[base+s];
    #pragma unroll
    for (int q = 0; q < 4; ++q)
      *(float4*)&bij[s*20 + 4*q] = *(const float4*)&gates_rs[(base+s)*A_ + 4*q];
  }
  __syncthreads();

  if (t < S_ && !padl[t]) {
    atomicAdd(&counts[idxl[t]], 1);
    atomicMax(&maxpos[idxl[t]], t + 1);
  }
  // gates softmax -> overwrite OUT1
  if (t < S_) {
    int s = t;
    float row[16]; float mx = -3.0e38f;
    #pragma unroll
    for (int a = 0; a < 16; ++a) { row[a] = bij[s*20+a]; mx = fmaxf(mx, row[a]); }
    float sm = 0.f;
    #pragma unroll
    for (int a = 0; a < 16; ++a) { row[a] = expf(row[a] - mx); sm += row[a]; }
    float inv = 1.f / sm;
    #pragma unroll
    for (int q = 0; q < 4; ++q) {
      float4 o; o.x=row[4*q]*inv; o.y=row[4*q+1]*inv; o.z=row[4*q+2]*inv; o.w=row[4*q+3]*inv;
      *(float4*)&gates_rs[(base+s)*A_ + 4*q] = o;
    }
  }
  // tma = softmax(w)
  float mxw = blk_max(wv, red);
  float ev = (t < S_) ? expf(wv - mxw) : 0.f;
  float sw = blk_sum(ev, red);
  if (t < S_) tmaL[t] = ev / sw;
  __syncthreads();
  if (t < A_) {
    int c = counts[t];
    float mkv = (c == 0) ? 1.f : 0.f;
    maskf[t] = mkv;
    mask_out[b*A_ + t] = mkv;
    int mp = maxpos[t];
    aidx_out[b*A_ + t] = (mp > 0) ? (float)(mp - 1) : -1.f;
  }
  __syncthreads();

  for (int iter = 0; iter < 3; ++iter) {
    // ---- step1: wgtT[a][s] = bf16( softmax_a(mask? NEG : bij)[a] * (pad?0:tma) ) ----
    if (t < S_) {
      int s = t;
      float row[16]; float mx = -3.0e38f;
      #pragma unroll
      for (int a = 0; a < 16; ++a) {
        float v = bij[s*20+a];
        v = (maskf[a] > 0.5f) ? NEGV : v;
        row[a] = v; mx = fmaxf(mx, v);
      }
      float sm = 0.f;
      #pragma unroll
      for (int a = 0; a < 16; ++a) { row[a] = expf(row[a] - mx); sm += row[a]; }
      float sc = (padl[s] ? 0.f : tmaL[s]) / sm;
      #pragma unroll
      for (int a = 0; a < 16; ++a) wgtT[a*WGSTR + s] = bf16u(row[a]*sc);
    }
    __syncthreads();

    // ---- step2: D[h][a] = sum_s moe(s,h) * wgt(s,a); wave w owns h-tile w ----
    f32x4 acc = (f32x4){0.f,0.f,0.f,0.f};
    {
      unsigned vA = (unsigned)(w*7168 + lane*8);   // byte addr into moeTr
      #pragma unroll
      for (int ks = 0; ks < 7; ++ks) {
        unsigned vAk = vA + (unsigned)(ks*1024);
        long long r0, r1;
        asm volatile(
          "ds_read_b64_tr_b16 %0, %2\n\t"
          "ds_read_b64_tr_b16 %1, %2 offset:512\n\t"
          "s_waitcnt lgkmcnt(0)"
          : "=&v"(r0), "=&v"(r1) : "v"(vAk) : "memory");
        __builtin_amdgcn_sched_barrier(0);
        union { short8 v; long long q[2]; } uu;
        uu.q[0] = r0; uu.q[1] = r1;
        short8 bf = *(const short8*)&wgtT[la*WGSTR + ks*32 + lg*8];
        acc = __builtin_amdgcn_mfma_f32_16x16x32_bf16(uu.v, bf, acc, 0, 0, 0);
      }
    }
    // ---- step3: squash. lane holds cap(a=la, h = 16w + 4*lg + r) ----
    {
      float n2 = acc[0]*acc[0] + acc[1]*acc[1] + acc[2]*acc[2] + acc[3]*acc[3];
      n2 += __shfl_xor(n2, 16);
      n2 += __shfl_xor(n2, 32);
      if (lane < 16) n2p[w*17 + lane] = n2;
    }
    __syncthreads();
    if (t < 16) {
      float sv = 0.f;
      #pragma unroll
      for (int w2 = 0; w2 < 16; ++w2) sv += n2p[w2*17 + t];
      n2s[t] = sv / (1.f + sv) / sqrtf(sv + 1e-9f);
    }
    __syncthreads();
    {
      float sc = n2s[la];
      if (iter < 2) {
        #pragma unroll
        for (int r = 0; r < 4; ++r)
          capB[la*CBSTR + w*16 + lg*4 + r] = bf16u(acc[r]*sc);
      } else {
        float* capl = bij;  // bij dead after this iter's step1
        #pragma unroll
        for (int r = 0; r < 4; ++r)
          capl[la*CLSTR + w*16 + lg*4 + r] = acc[r]*sc;
      }
    }
    __syncthreads();

    // ---- step4: bij[s][a] += sum_h moe(s,h)*cap(a,h); wave w owns s-tile w ----
    if (iter < 2) {
      if (w < 13) {
        int sR = w*16 + la;            // A-read row (may be >=200 on tile 12: zeroed region)
        int ksS = sR >> 5, s4l = (sR >> 2) & 7, sr = sR & 3;
        int bp = (s4l & 1) ? 4 + (s4l >> 1) : (s4l >> 1);
        int laneA = ksS*512 + bp*64 + sr*16 + (lg & 1)*8 + (lg >> 1)*3584;
        f32x4 accS = (f32x4){0.f,0.f,0.f,0.f};
        #pragma unroll
        for (int k4 = 0; k4 < 8; ++k4) {
          short8 am = *(const short8*)&moeTr[laneA + k4*7168];
          short8 bc = *(const short8*)&capB[la*CBSTR + k4*32 + lg*8];
          accS = __builtin_amdgcn_mfma_f32_16x16x32_bf16(am, bc, accS, 0, 0, 0);
        }
        int sW = w*16 + lg*4;
        #pragma unroll
        for (int r = 0; r < 4; ++r)
          if (sW + r < S_) bij[(sW + r)*20 + la] += accS[r];
      }
      __syncthreads();
    }
  }

  // ---- final cap write (from capl f32, aliased over bij) ----
  {
    const float* capl = bij;
    #pragma unroll
    for (int q = 0; q < 4; ++q) {
      int e = t + 1024*q;
      int a = e >> 8, h = e & 255;
      cap_out[((size_t)b*A_ + a)*H_ + h] = capl[a*CLSTR + h];
    }
    // activated[b,s,:] = cap[b, idx[b,s], :]
    int h4 = t & 63;
    for (int s = t >> 6; s < S_; s += 16) {
      float4 v = *(const float4*)&capl[idxl[s]*CLSTR + 4*h4];
      *(float4*)&act_out[((size_t)base + s)*H_ + 4*h4] = v;
    }
  }
}

extern "C" void kernel_launch(void* const* d_in, const int* in_sizes, int n_in,
                              void* d_out, int out_size, void* d_ws, size_t ws_size,
                              hipStream_t stream) {
  (void)in_sizes; (void)n_in; (void)out_size; (void)ws_size;
  const float* item  = (const float*)d_in[0];
  const int*   iseq  = (const int*)d_in[1];
  const int*   tseq  = (const int*)d_in[2];
  const float* W_lin = (const float*)d_in[3];
  const float* b_lin = (const float*)d_in[4];
  const float* asp   = (const float*)d_in[5];
  const float* pos   = (const float*)d_in[6];
  const float* tdt   = (const float*)d_in[7];
  const float* tdn   = (const float*)d_in[8];
  const float* Wa1   = (const float*)d_in[9];
  const float* ba1   = (const float*)d_in[10];
  const float* Wa2   = (const float*)d_in[11];
  const float* ba2   = (const float*)d_in[12];
  const float* g_ln  = (const float*)d_in[13];
  const float* b_ln  = (const float*)d_in[14];

  float* out    = (float*)d_out;
  float* cap_o  = out;                 // B*A*H     = 262144
  float* gate_o = out + 262144;        // B*S*A     = 204800
  float* mask_o = out + 466944;        // B*A       = 1024
  float* act_o  = out + 467968;        // B*S*H     = 3276800 (bf16 scratch, then activated)
  float* aidx_o = out + 3744768;       // B*A       = 1024
  float* idx_o  = out + 3745792;       // B*S       = 12800

  // scratch in d_ws: moeB bf16 (6.55MB) | Wa1T bf16 | WlinT bf16 | w f32
  ushortT* moeB  = (ushortT*)d_ws;
  ushortT* Wa1T  = (ushortT*)((char*)d_ws + 6553600);
  ushortT* WlinT = Wa1T + 65536;
  float*   w_ws  = (float*)((char*)d_ws + 6553600 + 262144);

  // bf16 activations live in the act_o region until phaseC overwrites it
  ushortT* itemB = (ushortT*)act_o;
  ushortT* tmaB  = itemB + (size_t)M_*H_;

  prep_kernel<<<832, 256, 0, stream>>>(item, iseq, tseq, Wa1, W_lin, asp,
      pos, tdt, tdn, itemB, tmaB, Wa1T, WlinT, gate_o, idx_o);
  gemm_kernel<<<dim3(M_/64, 2), 256, 0, stream>>>(tmaB, itemB, Wa1T, WlinT,
      item, iseq, ba1, Wa2, ba2, b_lin, g_ln, b_ln, w_ws, moeB);
  phaseC_kernel<<<B_, 1024, 0, stream>>>(iseq, w_ws, moeB, idx_o,
      gate_o, cap_o, mask_o, aidx_o, act_o);
}

// Round 5
// 59.526 us; speedup vs baseline: 4.4505x; 1.0246x over previous
//
#include <hip/hip_runtime.h>

#define B_ 64
#define S_ 200
#define H_ 256
#define A_ 16
#define M_ (B_*S_)
#define NEGV (-1000000000.0f)

typedef unsigned short ushortT;
typedef __attribute__((ext_vector_type(8))) short short8;
typedef __attribute__((ext_vector_type(4))) float f32x4;

__device__ __forceinline__ ushortT bf16u(float f) {
  unsigned int u = __builtin_bit_cast(unsigned int, f);
  unsigned int r = (u + 0x7fffu + ((u >> 16) & 1u)) >> 16;
  return (ushortT)r;
}
__device__ __forceinline__ float bf2f(ushortT u) {
  unsigned int v = ((unsigned int)u) << 16;
  return __builtin_bit_cast(float, v);
}

// ---------------- prep: weight transposes + gates/idx (f32-exact) ----------------
__global__ __launch_bounds__(256) void prep_kernel(
    const float* __restrict__ item, const float* __restrict__ Wa1,
    const float* __restrict__ W_lin, const float* __restrict__ asp,
    ushortT* __restrict__ Wa1T, ushortT* __restrict__ WlinT,
    float* __restrict__ gates_raw, float* __restrict__ idxf)
{
  const int blk = blockIdx.x;
  const int t = threadIdx.x;

  if (blk >= 800) {
    __shared__ float T[64*65];
    int wsel = (blk - 800) >> 4;
    int tile = (blk - 800) & 15;
    const float* W = wsel ? W_lin : Wa1;
    ushortT* WT = wsel ? WlinT : Wa1T;
    int tr = (tile >> 2) * 64, tc = (tile & 3) * 64;
    #pragma unroll
    for (int p = 0; p < 16; ++p) {
      int r = p*4 + (t >> 6);
      int c = t & 63;
      T[c*65 + r] = W[(tr + r)*H_ + tc + c];
    }
    __syncthreads();
    #pragma unroll
    for (int p = 0; p < 16; ++p) {
      int n = p*4 + (t >> 6);
      int k = t & 63;
      WT[(tc + n)*H_ + tr + k] = bf16u(T[n*65 + k]);
    }
    return;
  }

  __shared__ float aspl[16*260];
  __shared__ float gL[16*20];

  const int m0 = blk * 16;
  #pragma unroll
  for (int i = 0; i < 4; ++i) {
    int e = t + 256*i;
    int r = e >> 6, c = e & 63;
    *(float4*)&aspl[r*260 + 4*c] = *(const float4*)&asp[r*H_ + 4*c];
  }
  __syncthreads();

  {
    int r = t >> 4, a = t & 15;
    int m = m0 + r;
    float g = 0.f;
    #pragma unroll 4
    for (int k4 = 0; k4 < 64; ++k4) {
      float4 xv = *(const float4*)&item[(size_t)m*H_ + 4*k4];
      float4 av = *(const float4*)&aspl[a*260 + 4*k4];
      g += xv.x*av.x + xv.y*av.y + xv.z*av.z + xv.w*av.w;
    }
    gL[r*20 + a] = g;
  }
  __syncthreads();
  if (t < 64) {
    int r = t >> 2, q = t & 3;
    float4 gv;
    gv.x = gL[r*20 + 4*q + 0]; gv.y = gL[r*20 + 4*q + 1];
    gv.z = gL[r*20 + 4*q + 2]; gv.w = gL[r*20 + 4*q + 3];
    *(float4*)&gates_raw[(m0+r)*A_ + 4*q] = gv;
  }
  if (t < 16) {
    float best = gL[t*20]; int bi = 0;
    #pragma unroll
    for (int a = 1; a < 16; ++a) {
      float v = gL[t*20 + a];
      if (v > best) { best = v; bi = a; }
    }
    idxf[m0 + t] = (float)bi;
  }
}

// ---------------- fused dual MFMA GEMM: 200 blocks x 512 thr ----------------
// Waves 0-3: tma_in @ Wa1 -> w epilogue.  Waves 4-7: item @ W_lin -> moe epilogue.
// Per k-step: item f32 staged once, converted to bf16 (tma adds pos/td); both
// B-tiles staged; 16 MFMA per wave.
__global__ __launch_bounds__(512, 2) void gemm_kernel(
    const float* __restrict__ item, const int* __restrict__ iseq,
    const int* __restrict__ tseq, const float* __restrict__ pos,
    const float* __restrict__ tdt, const float* __restrict__ tdn,
    const ushortT* __restrict__ Wa1T, const ushortT* __restrict__ WlinT,
    const float* __restrict__ ba1, const float* __restrict__ Wa2,
    const float* __restrict__ ba2, const float* __restrict__ b_lin,
    const float* __restrict__ g_ln, const float* __restrict__ b_ln,
    float* __restrict__ w_out, ushortT* __restrict__ moe_outB)
{
  __shared__ ushortT Atma[64*40];
  __shared__ ushortT Aitm[64*40];
  __shared__ ushortT B0l[256*40];
  __shared__ ushortT B1l[256*40];
  __shared__ int sL[64], ttL[64], tnL[64];

  const int t = threadIdx.x;
  const int m0 = blockIdx.x * 64;
  const int lane = t & 63, w = t >> 6;
  const int g = w >> 2, wl = w & 3;
  const int col = lane & 15;
  const int rg  = lane >> 4;

  if (t < 64) {
    int m = m0 + t;
    sL[t]  = m % S_;
    ttL[t] = tseq[2*m];
    tnL[t] = tseq[2*m+1];
  }

  f32x4 acc[16];
  #pragma unroll
  for (int i = 0; i < 16; ++i) acc[i] = (f32x4){0.f,0.f,0.f,0.f};

  const int ar = t >> 3, kq = (t & 7) * 4;   // A-stage: row, 4-k chunk
  const int nr = t >> 1, kh = (t & 1) * 16;  // B-stage: n-row, 16-k half

  __syncthreads();  // sL ready

  for (int k0 = 0; k0 < H_; k0 += 32) {
    // A: load item f32 + tma terms, convert to bf16
    float4 iv = *(const float4*)&item[(size_t)(m0 + ar)*H_ + k0 + kq];
    float4 pv = *(const float4*)&pos[sL[ar]*H_ + k0 + kq];
    float4 tv = *(const float4*)&tdt[ttL[ar]*H_ + k0 + kq];
    float4 nv = *(const float4*)&tdn[tnL[ar]*H_ + k0 + kq];
    union { ushortT u[4]; uint2 v; } ci, ct;
    ci.u[0] = bf16u(iv.x); ci.u[1] = bf16u(iv.y);
    ci.u[2] = bf16u(iv.z); ci.u[3] = bf16u(iv.w);
    ct.u[0] = bf16u(iv.x + pv.x + tv.x + nv.x);
    ct.u[1] = bf16u(iv.y + pv.y + tv.y + nv.y);
    ct.u[2] = bf16u(iv.z + pv.z + tv.z + nv.z);
    ct.u[3] = bf16u(iv.w + pv.w + tv.w + nv.w);
    // B: both weights, 2 uint4 each
    uint4 b0a = *(const uint4*)&Wa1T[(size_t)nr*H_ + k0 + kh];
    uint4 b0b = *(const uint4*)&Wa1T[(size_t)nr*H_ + k0 + kh + 8];
    uint4 b1a = *(const uint4*)&WlinT[(size_t)nr*H_ + k0 + kh];
    uint4 b1b = *(const uint4*)&WlinT[(size_t)nr*H_ + k0 + kh + 8];
    __syncthreads();   // prior compute done before overwrite
    *(uint2*)&Aitm[ar*40 + kq] = ci.v;
    *(uint2*)&Atma[ar*40 + kq] = ct.v;
    *(uint4*)&B0l[nr*40 + kh]     = b0a;
    *(uint4*)&B0l[nr*40 + kh + 8] = b0b;
    *(uint4*)&B1l[nr*40 + kh]     = b1a;
    *(uint4*)&B1l[nr*40 + kh + 8] = b1b;
    __syncthreads();
    const ushortT* Ab = g ? Aitm : Atma;
    const ushortT* Bb = g ? B1l : B0l;
    short8 af = *(const short8*)&Ab[(wl*16 + col)*40 + rg*8];
    #pragma unroll
    for (int q = 0; q < 16; ++q) {
      short8 bf = *(const short8*)&Bb[(q*16 + col)*40 + rg*8];
      acc[q] = __builtin_amdgcn_mfma_f32_16x16x32_bf16(af, bf, acc[q], 0, 0, 0);
    }
  }

  if (g == 0) {
    float bav[16], wav[16];
    #pragma unroll
    for (int q = 0; q < 16; ++q) {
      int n = q*16 + col;
      bav[q] = ba1[n]; wav[q] = Wa2[n];
    }
    float bb2 = ba2[0];
    #pragma unroll
    for (int j = 0; j < 4; ++j) {
      float p = 0.f;
      #pragma unroll
      for (int q = 0; q < 16; ++q) {
        float h = acc[q][j] + bav[q];
        h = (h >= 0.f) ? h : 0.01f*h;
        p += h * wav[q];
      }
      #pragma unroll
      for (int mk = 1; mk < 16; mk <<= 1) p += __shfl_xor(p, mk);
      if (col == 0) {
        int m = m0 + wl*16 + rg*4 + j;
        w_out[m] = (iseq[m] == 0) ? NEGV : (p + bb2);
      }
    }
  } else {
    float blv[16], glv[16], bbv[16];
    #pragma unroll
    for (int q = 0; q < 16; ++q) {
      int n = q*16 + col;
      blv[q] = b_lin[n]; glv[q] = g_ln[n]; bbv[q] = b_ln[n];
    }
    #pragma unroll
    for (int j = 0; j < 4; ++j) {
      int m = m0 + wl*16 + rg*4 + j;
      float v[16];
      float s1 = 0.f, s2 = 0.f;
      #pragma unroll
      for (int q = 0; q < 16; ++q) {
        float ivv = item[(size_t)m*H_ + q*16 + col];
        float vv = tanhf(acc[q][j] + blv[q]) + ivv;
        v[q] = vv; s1 += vv; s2 += vv*vv;
      }
      #pragma unroll
      for (int mk = 1; mk < 16; mk <<= 1) {
        s1 += __shfl_xor(s1, mk);
        s2 += __shfl_xor(s2, mk);
      }
      float mu  = s1 * (1.0f/H_);
      float var = s2 * (1.0f/H_) - mu*mu;
      float rs  = 1.0f / sqrtf(fmaxf(var, 0.f) + 1e-12f);
      #pragma unroll
      for (int q = 0; q < 16; ++q)
        moe_outB[(size_t)m*H_ + q*16 + col] = bf16u((v[q] - mu)*rs*glv[q] + bbv[q]);
    }
  }
}

// ---------------- Phase C: MFMA routing (one block per batch) ----------------
__device__ __forceinline__ float blk_max(float v, float* red) {
  #pragma unroll
  for (int mk = 32; mk; mk >>= 1) v = fmaxf(v, __shfl_xor(v, mk));
  int t = threadIdx.x;
  if ((t & 63) == 0) red[t >> 6] = v;
  __syncthreads();
  if (t < 64) {
    float x = (t < 16) ? red[t] : -3.0e38f;
    #pragma unroll
    for (int mk = 8; mk; mk >>= 1) x = fmaxf(x, __shfl_xor(x, mk));
    if (t == 0) red[0] = x;
  }
  __syncthreads();
  float r = red[0];
  __syncthreads();
  return r;
}

__device__ __forceinline__ float blk_sum(float v, float* red) {
  #pragma unroll
  for (int mk = 32; mk; mk >>= 1) v += __shfl_xor(v, mk);
  int t = threadIdx.x;
  if ((t & 63) == 0) red[t >> 6] = v;
  __syncthreads();
  if (t < 64) {
    float x = (t < 16) ? red[t] : 0.f;
    #pragma unroll
    for (int mk = 8; mk; mk >>= 1) x += __shfl_xor(x, mk);
    if (t == 0) red[0] = x;
  }
  __syncthreads();
  float r = red[0];
  __syncthreads();
  return r;
}

// moeTr layout: [ht=16][ks=7][bp=8][sr=4][hc=16] bf16, where for s:
//   ks=s/32, s4l=(s/4)%8, bp = even s4l -> s4l/2, odd -> 4+s4l/2, sr=s%4.
// Serves: step2 A-operand (k=s) via ds_read_b64_tr_b16 (linear vaddr=base+lane*8),
//         step4 A-operand (k=h) via natural ds_read_b128.
#define WGSTR 232   // wgtT stride (bf16), s padded to 224 + bank skew
#define CBSTR 260   // capB stride (bf16)
#define CLSTR 252   // capl stride (f32), 16B-aligned rows

__global__ __launch_bounds__(1024) void phaseC_kernel(
    const int* __restrict__ iseq, const float* __restrict__ w_in,
    const ushortT* __restrict__ moeB, const float* __restrict__ idxf,
    float* __restrict__ gates_rs,   // raw in -> softmax out (OUT1)
    float* __restrict__ cap_out,    // OUT0
    float* __restrict__ mask_out,   // OUT2
    float* __restrict__ aidx_out,   // OUT4
    float* __restrict__ act_out)    // OUT3 (activated)
{
  __shared__ ushortT moeTr[57344];  // 114688 B
  __shared__ ushortT wgtT[16*WGSTR];// 7424 B
  __shared__ ushortT capB[16*CBSTR];// 8320 B
  __shared__ float bij[4032];       // 16128 B; capl f32 [16][252] aliases after last bij read
  __shared__ float n2p[16*17];
  __shared__ float n2s[16];
  __shared__ float tmaL[S_];
  __shared__ float red[16];
  __shared__ float maskf[A_];
  __shared__ int counts[A_], maxpos[A_];
  __shared__ int idxl[S_];
  __shared__ int padl[S_];

  const int t = threadIdx.x;
  const int b = blockIdx.x;
  const int base = b * S_;
  const int lane = t & 63, w = t >> 6;
  const int la = lane & 15, lg = lane >> 4;

  // ---- stage moe (bf16) into permuted LDS layout; zero s-tail [200,224) ----
  #pragma unroll
  for (int u = 0; u < 4; ++u) {
    int e = t + 1024*u;               // e = s*16 + ht  (coalesced global reads)
    if (e < 3584) {
      int ht = e & 15, s = e >> 4;
      int ks = s >> 5, s4l = (s >> 2) & 7, sr = s & 3;
      int bp = (s4l & 1) ? 4 + (s4l >> 1) : (s4l >> 1);
      int li = ((ht*7 + ks)*8 + bp)*64 + sr*16;
      if (s < S_) {
        const ushortT* gp = &moeB[((size_t)(base + s))*H_ + ht*16];
        *(uint4*)&moeTr[li]     = *(const uint4*)gp;
        *(uint4*)&moeTr[li + 8] = *(const uint4*)(gp + 8);
      } else {
        uint4 z = {0,0,0,0};
        *(uint4*)&moeTr[li] = z; *(uint4*)&moeTr[li + 8] = z;
      }
    }
  }
  // zero wgtT s-tail [200,232)
  if (t < 512) {
    int a = t >> 5, s = 200 + (t & 31);
    wgtT[a*WGSTR + s] = 0;
  }

  if (t < A_) { counts[t] = 0; maxpos[t] = -1; }
  float wv = -3.0e38f;
  if (t < S_) {
    int s = t;
    padl[s] = (iseq[base+s] == 0) ? 1 : 0;
    idxl[s] = (int)idxf[base+s];
    wv = w_in[base+s];
    #pragma unroll
    for (int q = 0; q < 4; ++q)
      *(float4*)&bij[s*20 + 4*q] = *(const float4*)&gates_rs[(base+s)*A_ + 4*q];
  }
  __syncthreads();

  if (t < S_ && !padl[t]) {
    atomicAdd(&counts[idxl[t]], 1);
    atomicMax(&maxpos[idxl[t]], t + 1);
  }
  // gates softmax -> overwrite OUT1
  if (t < S_) {
    int s = t;
    float row[16]; float mx = -3.0e38f;
    #pragma unroll
    for (int a = 0; a < 16; ++a) { row[a] = bij[s*20+a]; mx = fmaxf(mx, row[a]); }
    float sm = 0.f;
    #pragma unroll
    for (int a = 0; a < 16; ++a) { row[a] = expf(row[a] - mx); sm += row[a]; }
    float inv = 1.f / sm;
    #pragma unroll
    for (int q = 0; q < 4; ++q) {
      float4 o; o.x=row[4*q]*inv; o.y=row[4*q+1]*inv; o.z=row[4*q+2]*inv; o.w=row[4*q+3]*inv;
      *(float4*)&gates_rs[(base+s)*A_ + 4*q] = o;
    }
  }
  // tma = softmax(w)
  float mxw = blk_max(wv, red);
  float ev = (t < S_) ? expf(wv - mxw) : 0.f;
  float sw = blk_sum(ev, red);
  if (t < S_) tmaL[t] = ev / sw;
  __syncthreads();
  if (t < A_) {
    int c = counts[t];
    float mkv = (c == 0) ? 1.f : 0.f;
    maskf[t] = mkv;
    mask_out[b*A_ + t] = mkv;
    int mp = maxpos[t];
    aidx_out[b*A_ + t] = (mp > 0) ? (float)(mp - 1) : -1.f;
  }
  __syncthreads();

  for (int iter = 0; iter < 3; ++iter) {
    // ---- step1: wgtT[a][s] = bf16( softmax_a(mask? NEG : bij)[a] * (pad?0:tma) ) ----
    if (t < S_) {
      int s = t;
      float row[16]; float mx = -3.0e38f;
      #pragma unroll
      for (int a = 0; a < 16; ++a) {
        float v = bij[s*20+a];
        v = (maskf[a] > 0.5f) ? NEGV : v;
        row[a] = v; mx = fmaxf(mx, v);
      }
      float sm = 0.f;
      #pragma unroll
      for (int a = 0; a < 16; ++a) { row[a] = expf(row[a] - mx); sm += row[a]; }
      float sc = (padl[s] ? 0.f : tmaL[s]) / sm;
      #pragma unroll
      for (int a = 0; a < 16; ++a) wgtT[a*WGSTR + s] = bf16u(row[a]*sc);
    }
    __syncthreads();

    // ---- step2: D[h][a] = sum_s moe(s,h) * wgt(s,a); wave w owns h-tile w ----
    f32x4 acc = (f32x4){0.f,0.f,0.f,0.f};
    {
      unsigned vA = (unsigned)(w*7168 + lane*8);   // byte addr into moeTr
      #pragma unroll
      for (int ks = 0; ks < 7; ++ks) {
        unsigned vAk = vA + (unsigned)(ks*1024);
        long long r0, r1;
        asm volatile(
          "ds_read_b64_tr_b16 %0, %2\n\t"
          "ds_read_b64_tr_b16 %1, %2 offset:512\n\t"
          "s_waitcnt lgkmcnt(0)"
          : "=&v"(r0), "=&v"(r1) : "v"(vAk) : "memory");
        __builtin_amdgcn_sched_barrier(0);
        union { short8 v; long long q[2]; } uu;
        uu.q[0] = r0; uu.q[1] = r1;
        short8 bf = *(const short8*)&wgtT[la*WGSTR + ks*32 + lg*8];
        acc = __builtin_amdgcn_mfma_f32_16x16x32_bf16(uu.v, bf, acc, 0, 0, 0);
      }
    }
    // ---- step3: squash. lane holds cap(a=la, h = 16w + 4*lg + r) ----
    {
      float n2 = acc[0]*acc[0] + acc[1]*acc[1] + acc[2]*acc[2] + acc[3]*acc[3];
      n2 += __shfl_xor(n2, 16);
      n2 += __shfl_xor(n2, 32);
      if (lane < 16) n2p[w*17 + lane] = n2;
    }
    __syncthreads();
    if (t < 16) {
      float sv = 0.f;
      #pragma unroll
      for (int w2 = 0; w2 < 16; ++w2) sv += n2p[w2*17 + t];
      n2s[t] = sv / (1.f + sv) / sqrtf(sv + 1e-9f);
    }
    __syncthreads();
    {
      float sc = n2s[la];
      if (iter < 2) {
        #pragma unroll
        for (int r = 0; r < 4; ++r)
          capB[la*CBSTR + w*16 + lg*4 + r] = bf16u(acc[r]*sc);
      } else {
        float* capl = bij;  // bij dead after this iter's step1
        #pragma unroll
        for (int r = 0; r < 4; ++r)
          capl[la*CLSTR + w*16 + lg*4 + r] = acc[r]*sc;
      }
    }
    __syncthreads();

    // ---- step4: bij[s][a] += sum_h moe(s,h)*cap(a,h); wave w owns s-tile w ----
    if (iter < 2) {
      if (w < 13) {
        int sR = w*16 + la;            // A-read row (>=200 rows hit zeroed region)
        int ksS = sR >> 5, s4l = (sR >> 2) & 7, sr = sR & 3;
        int bp = (s4l & 1) ? 4 + (s4l >> 1) : (s4l >> 1);
        int laneA = ksS*512 + bp*64 + sr*16 + (lg & 1)*8 + (lg >> 1)*3584;
        f32x4 accS = (f32x4){0.f,0.f,0.f,0.f};
        #pragma unroll
        for (int k4 = 0; k4 < 8; ++k4) {
          short8 am = *(const short8*)&moeTr[laneA + k4*7168];
          short8 bc = *(const short8*)&capB[la*CBSTR + k4*32 + lg*8];
          accS = __builtin_amdgcn_mfma_f32_16x16x32_bf16(am, bc, accS, 0, 0, 0);
        }
        int sW = w*16 + lg*4;
        #pragma unroll
        for (int r = 0; r < 4; ++r)
          if (sW + r < S_) bij[(sW + r)*20 + la] += accS[r];
      }
      __syncthreads();
    }
  }

  // ---- final cap write (from capl f32, aliased over bij) ----
  {
    const float* capl = bij;
    #pragma unroll
    for (int q = 0; q < 4; ++q) {
      int e = t + 1024*q;
      int a = e >> 8, h = e & 255;
      cap_out[((size_t)b*A_ + a)*H_ + h] = capl[a*CLSTR + h];
    }
    // activated[b,s,:] = cap[b, idx[b,s], :]
    int h4 = t & 63;
    for (int s = t >> 6; s < S_; s += 16) {
      float4 v = *(const float4*)&capl[idxl[s]*CLSTR + 4*h4];
      *(float4*)&act_out[((size_t)base + s)*H_ + 4*h4] = v;
    }
  }
}

extern "C" void kernel_launch(void* const* d_in, const int* in_sizes, int n_in,
                              void* d_out, int out_size, void* d_ws, size_t ws_size,
                              hipStream_t stream) {
  (void)in_sizes; (void)n_in; (void)out_size; (void)ws_size;
  const float* item  = (const float*)d_in[0];
  const int*   iseq  = (const int*)d_in[1];
  const int*   tseq  = (const int*)d_in[2];
  const float* W_lin = (const float*)d_in[3];
  const float* b_lin = (const float*)d_in[4];
  const float* asp   = (const float*)d_in[5];
  const float* pos   = (const float*)d_in[6];
  const float* tdt   = (const float*)d_in[7];
  const float* tdn   = (const float*)d_in[8];
  const float* Wa1   = (const float*)d_in[9];
  const float* ba1   = (const float*)d_in[10];
  const float* Wa2   = (const float*)d_in[11];
  const float* ba2   = (const float*)d_in[12];
  const float* g_ln  = (const float*)d_in[13];
  const float* b_ln  = (const float*)d_in[14];

  float* out    = (float*)d_out;
  float* cap_o  = out;                 // B*A*H     = 262144
  float* gate_o = out + 262144;        // B*S*A     = 204800
  float* mask_o = out + 466944;        // B*A       = 1024
  float* act_o  = out + 467968;        // B*S*H     = 3276800
  float* aidx_o = out + 3744768;       // B*A       = 1024
  float* idx_o  = out + 3745792;       // B*S       = 12800

  // scratch in d_ws: moeB bf16 (6.55MB) | Wa1T bf16 | WlinT bf16 | w f32
  ushortT* moeB  = (ushortT*)d_ws;
  ushortT* Wa1T  = (ushortT*)((char*)d_ws + 6553600);
  ushortT* WlinT = Wa1T + 65536;
  float*   w_ws  = (float*)((char*)d_ws + 6553600 + 262144);

  prep_kernel<<<832, 256, 0, stream>>>(item, Wa1, W_lin, asp,
      Wa1T, WlinT, gate_o, idx_o);
  gemm_kernel<<<200, 512, 0, stream>>>(item, iseq, tseq, pos, tdt, tdn,
      Wa1T, WlinT, ba1, Wa2, ba2, b_lin, g_ln, b_ln, w_ws, moeB);
  phaseC_kernel<<<B_, 1024, 0, stream>>>(iseq, w_ws, moeB, idx_o,
      gate_o, cap_o, mask_o, aidx_o, act_o);
}

// Round 6
// 58.798 us; speedup vs baseline: 4.5056x; 1.0124x over previous
//
#include <hip/hip_runtime.h>

#define B_ 64
#define S_ 200
#define H_ 256
#define A_ 16
#define M_ (B_*S_)
#define NEGV (-1000000000.0f)

typedef unsigned short ushortT;
typedef __attribute__((ext_vector_type(8))) short short8;
typedef __attribute__((ext_vector_type(4))) float f32x4;

__device__ __forceinline__ ushortT bf16u(float f) {
  unsigned int u = __builtin_bit_cast(unsigned int, f);
  unsigned int r = (u + 0x7fffu + ((u >> 16) & 1u)) >> 16;
  return (ushortT)r;
}
__device__ __forceinline__ float bf2f(ushortT u) {
  unsigned int v = ((unsigned int)u) << 16;
  return __builtin_bit_cast(float, v);
}

// ---------------- prep: weight transposes + gates f32 (raw->ws, softmax->OUT1, idx) ----------------
__global__ __launch_bounds__(256) void prep_kernel(
    const float* __restrict__ item, const float* __restrict__ Wa1,
    const float* __restrict__ W_lin, const float* __restrict__ asp,
    ushortT* __restrict__ Wa1T, ushortT* __restrict__ WlinT,
    float* __restrict__ graw, float* __restrict__ gates_sm,
    float* __restrict__ idxf)
{
  const int blk = blockIdx.x;
  const int t = threadIdx.x;

  if (blk >= 800) {
    __shared__ float T[64*65];
    int wsel = (blk - 800) >> 4;
    int tile = (blk - 800) & 15;
    const float* W = wsel ? W_lin : Wa1;
    ushortT* WT = wsel ? WlinT : Wa1T;
    int tr = (tile >> 2) * 64, tc = (tile & 3) * 64;
    #pragma unroll
    for (int p = 0; p < 16; ++p) {
      int r = p*4 + (t >> 6);
      int c = t & 63;
      T[c*65 + r] = W[(tr + r)*H_ + tc + c];
    }
    __syncthreads();
    #pragma unroll
    for (int p = 0; p < 16; ++p) {
      int n = p*4 + (t >> 6);
      int k = t & 63;
      WT[(tc + n)*H_ + tr + k] = bf16u(T[n*65 + k]);
    }
    return;
  }

  __shared__ float aspl[16*260];
  __shared__ float gL[16*20];

  const int m0 = blk * 16;
  #pragma unroll
  for (int i = 0; i < 4; ++i) {
    int e = t + 256*i;
    int r = e >> 6, c = e & 63;
    *(float4*)&aspl[r*260 + 4*c] = *(const float4*)&asp[r*H_ + 4*c];
  }
  __syncthreads();

  {
    int r = t >> 4, a = t & 15;
    int m = m0 + r;
    float g = 0.f;
    #pragma unroll 4
    for (int k4 = 0; k4 < 64; ++k4) {
      float4 xv = *(const float4*)&item[(size_t)m*H_ + 4*k4];
      float4 av = *(const float4*)&aspl[a*260 + 4*k4];
      g += xv.x*av.x + xv.y*av.y + xv.z*av.z + xv.w*av.w;
    }
    gL[r*20 + a] = g;
  }
  __syncthreads();
  if (t < 64) {
    int r = t >> 2, q = t & 3;
    float4 gv;
    gv.x = gL[r*20 + 4*q + 0]; gv.y = gL[r*20 + 4*q + 1];
    gv.z = gL[r*20 + 4*q + 2]; gv.w = gL[r*20 + 4*q + 3];
    *(float4*)&graw[(m0+r)*A_ + 4*q] = gv;
  }
  if (t < 16) {
    int r = t;
    float best = gL[r*20]; int bi = 0;
    float mx = gL[r*20];
    #pragma unroll
    for (int a = 1; a < 16; ++a) {
      float v = gL[r*20 + a];
      if (v > best) { best = v; bi = a; }
      mx = fmaxf(mx, v);
    }
    idxf[m0 + r] = (float)bi;
    float ex[16]; float sm = 0.f;
    #pragma unroll
    for (int a = 0; a < 16; ++a) { ex[a] = expf(gL[r*20 + a] - mx); sm += ex[a]; }
    float inv = 1.f / sm;
    #pragma unroll
    for (int a = 0; a < 16; ++a) gates_sm[(m0+r)*A_ + a] = ex[a]*inv;
  }
}

// ---------------- fused dual MFMA GEMM, prefetched: 200 blocks x 512 thr ----------------
// Waves 0-3: tma@Wa1 (32x128 tiles, 2m x 2n). Waves 4-7: item@W_lin.
// A staged persistently [64][ASTR] bf16 (slice per k-step); B per-kstep, reg-prefetched.
#define ASTR 280
#define BSTR 40
__global__ __launch_bounds__(512) void gemm_kernel(
    const float* __restrict__ item, const int* __restrict__ iseq,
    const int* __restrict__ tseq, const float* __restrict__ pos,
    const float* __restrict__ tdt, const float* __restrict__ tdn,
    const ushortT* __restrict__ Wa1T, const ushortT* __restrict__ WlinT,
    const float* __restrict__ ba1, const float* __restrict__ Wa2,
    const float* __restrict__ ba2, const float* __restrict__ b_lin,
    const float* __restrict__ g_ln, const float* __restrict__ b_ln,
    float* __restrict__ w_out, ushortT* __restrict__ moe_outB)
{
  __shared__ ushortT Atma[64*ASTR];
  __shared__ ushortT Aitm[64*ASTR];
  __shared__ ushortT B0l[256*BSTR];
  __shared__ ushortT B1l[256*BSTR];
  __shared__ int sL[64], ttL[64], tnL[64];
  __shared__ float wp[2][64];
  __shared__ float ln1[2][64], ln2[2][64];
  __shared__ float mus[64], rss[64];

  const int t = threadIdx.x;
  const int m0 = blockIdx.x * 64;
  const int lane = t & 63, w = t >> 6;
  const int g = w >> 2, wl = w & 3;
  const int wm = wl >> 1, wn = wl & 1;
  const int col = lane & 15;
  const int rg  = lane >> 4;

  if (t < 64) {
    int m = m0 + t;
    sL[t]  = m % S_;
    ttL[t] = tseq[2*m];
    tnL[t] = tseq[2*m+1];
  }
  __syncthreads();

  const int arow = t >> 3;          // 0..63
  const int ac4  = (t & 7) * 4;     // 0..28
  const int nr   = t >> 1;          // 0..255
  const int kh   = (t & 1) * 16;
  const int srow = sL[arow], trow = ttL[arow], nrow = tnL[arow];

  // prefetch k-step 0
  float4 pi = *(const float4*)&item[(size_t)(m0+arow)*H_ + ac4];
  float4 pp = *(const float4*)&pos[srow*H_ + ac4];
  float4 pt = *(const float4*)&tdt[trow*H_ + ac4];
  float4 pn = *(const float4*)&tdn[nrow*H_ + ac4];
  uint4 b0a = *(const uint4*)&Wa1T[(size_t)nr*H_ + kh];
  uint4 b0b = *(const uint4*)&Wa1T[(size_t)nr*H_ + kh + 8];
  uint4 b1a = *(const uint4*)&WlinT[(size_t)nr*H_ + kh];
  uint4 b1b = *(const uint4*)&WlinT[(size_t)nr*H_ + kh + 8];

  f32x4 acc[2][8];
  #pragma unroll
  for (int r = 0; r < 2; ++r)
    #pragma unroll
    for (int q = 0; q < 8; ++q) acc[r][q] = (f32x4){0.f,0.f,0.f,0.f};

  #pragma unroll
  for (int ks = 0; ks < 8; ++ks) {
    const int k0 = ks*32;
    union { ushortT u[4]; uint2 v; } ci, ct;
    ci.u[0] = bf16u(pi.x); ci.u[1] = bf16u(pi.y);
    ci.u[2] = bf16u(pi.z); ci.u[3] = bf16u(pi.w);
    ct.u[0] = bf16u(pi.x + pp.x + pt.x + pn.x);
    ct.u[1] = bf16u(pi.y + pp.y + pt.y + pn.y);
    ct.u[2] = bf16u(pi.z + pp.z + pt.z + pn.z);
    ct.u[3] = bf16u(pi.w + pp.w + pt.w + pn.w);
    *(uint2*)&Aitm[arow*ASTR + k0 + ac4] = ci.v;
    *(uint2*)&Atma[arow*ASTR + k0 + ac4] = ct.v;
    *(uint4*)&B0l[nr*BSTR + kh]     = b0a;
    *(uint4*)&B0l[nr*BSTR + kh + 8] = b0b;
    *(uint4*)&B1l[nr*BSTR + kh]     = b1a;
    *(uint4*)&B1l[nr*BSTR + kh + 8] = b1b;
    if (ks < 7) {
      const int k1 = k0 + 32;
      pi = *(const float4*)&item[(size_t)(m0+arow)*H_ + k1 + ac4];
      pp = *(const float4*)&pos[srow*H_ + k1 + ac4];
      pt = *(const float4*)&tdt[trow*H_ + k1 + ac4];
      pn = *(const float4*)&tdn[nrow*H_ + k1 + ac4];
      b0a = *(const uint4*)&Wa1T[(size_t)nr*H_ + k1 + kh];
      b0b = *(const uint4*)&Wa1T[(size_t)nr*H_ + k1 + kh + 8];
      b1a = *(const uint4*)&WlinT[(size_t)nr*H_ + k1 + kh];
      b1b = *(const uint4*)&WlinT[(size_t)nr*H_ + k1 + kh + 8];
    }
    __syncthreads();   // stage visible
    const ushortT* Ab = g ? Aitm : Atma;
    const ushortT* Bb = g ? B1l : B0l;
    short8 af0 = *(const short8*)&Ab[(wm*32 + col)*ASTR + k0 + rg*8];
    short8 af1 = *(const short8*)&Ab[(wm*32 + 16 + col)*ASTR + k0 + rg*8];
    #pragma unroll
    for (int q = 0; q < 8; ++q) {
      short8 bf = *(const short8*)&Bb[(wn*128 + q*16 + col)*BSTR + rg*8];
      acc[0][q] = __builtin_amdgcn_mfma_f32_16x16x32_bf16(af0, bf, acc[0][q], 0, 0, 0);
      acc[1][q] = __builtin_amdgcn_mfma_f32_16x16x32_bf16(af1, bf, acc[1][q], 0, 0, 0);
    }
    if (ks < 7) __syncthreads();  // MFMA done before B overwrite
  }

  // ---- epilogue phase 1 ----
  float glv[8], bbv[8];
  if (g == 0) {
    float bav[8], wav[8];
    #pragma unroll
    for (int q = 0; q < 8; ++q) {
      int n = wn*128 + q*16 + col;
      bav[q] = ba1[n]; wav[q] = Wa2[n];
    }
    #pragma unroll
    for (int r = 0; r < 2; ++r)
      #pragma unroll
      for (int j = 0; j < 4; ++j) {
        float p = 0.f;
        #pragma unroll
        for (int q = 0; q < 8; ++q) {
          float h = acc[r][q][j] + bav[q];
          h = (h >= 0.f) ? h : 0.01f*h;
          p += h * wav[q];
        }
        #pragma unroll
        for (int mk = 1; mk < 16; mk <<= 1) p += __shfl_xor(p, mk);
        if (col == 0) wp[wn][wm*32 + r*16 + rg*4 + j] = p;
      }
  } else {
    float blv[8];
    #pragma unroll
    for (int q = 0; q < 8; ++q) {
      int n = wn*128 + q*16 + col;
      blv[q] = b_lin[n]; glv[q] = g_ln[n]; bbv[q] = b_ln[n];
    }
    #pragma unroll
    for (int r = 0; r < 2; ++r)
      #pragma unroll
      for (int j = 0; j < 4; ++j) {
        int row = wm*32 + r*16 + rg*4 + j;
        float s1 = 0.f, s2 = 0.f;
        #pragma unroll
        for (int q = 0; q < 8; ++q) {
          int n = wn*128 + q*16 + col;
          float vv = tanhf(acc[r][q][j] + blv[q]) + bf2f(Aitm[row*ASTR + n]);
          acc[r][q][j] = vv; s1 += vv; s2 += vv*vv;
        }
        #pragma unroll
        for (int mk = 1; mk < 16; mk <<= 1) {
          s1 += __shfl_xor(s1, mk);
          s2 += __shfl_xor(s2, mk);
        }
        if (col == 0) { ln1[wn][row] = s1; ln2[wn][row] = s2; }
      }
  }
  __syncthreads();
  if (t < 64) {
    int row = t, m = m0 + row;
    w_out[m] = (iseq[m] == 0) ? NEGV : (wp[0][row] + wp[1][row] + ba2[0]);
  } else if (t < 128) {
    int row = t - 64;
    float s1 = ln1[0][row] + ln1[1][row];
    float s2 = ln2[0][row] + ln2[1][row];
    float mu  = s1 * (1.0f/H_);
    float var = s2 * (1.0f/H_) - mu*mu;
    mus[row] = mu;
    rss[row] = 1.0f / sqrtf(fmaxf(var, 0.f) + 1e-12f);
  }
  __syncthreads();
  if (g == 1) {
    #pragma unroll
    for (int r = 0; r < 2; ++r)
      #pragma unroll
      for (int j = 0; j < 4; ++j) {
        int row = wm*32 + r*16 + rg*4 + j;
        int m = m0 + row;
        float mu = mus[row], rs = rss[row];
        #pragma unroll
        for (int q = 0; q < 8; ++q) {
          int n = wn*128 + q*16 + col;
          moe_outB[(size_t)m*H_ + n] = bf16u((acc[r][q][j] - mu)*rs*glv[q] + bbv[q]);
        }
      }
  }
}

// ---------------- Phase C: MFMA routing (one block per batch) ----------------
__device__ __forceinline__ float blk_max(float v, float* red) {
  #pragma unroll
  for (int mk = 32; mk; mk >>= 1) v = fmaxf(v, __shfl_xor(v, mk));
  int t = threadIdx.x;
  if ((t & 63) == 0) red[t >> 6] = v;
  __syncthreads();
  if (t < 64) {
    float x = (t < 16) ? red[t] : -3.0e38f;
    #pragma unroll
    for (int mk = 8; mk; mk >>= 1) x = fmaxf(x, __shfl_xor(x, mk));
    if (t == 0) red[0] = x;
  }
  __syncthreads();
  float r = red[0];
  __syncthreads();
  return r;
}

__device__ __forceinline__ float blk_sum(float v, float* red) {
  #pragma unroll
  for (int mk = 32; mk; mk >>= 1) v += __shfl_xor(v, mk);
  int t = threadIdx.x;
  if ((t & 63) == 0) red[t >> 6] = v;
  __syncthreads();
  if (t < 64) {
    float x = (t < 16) ? red[t] : 0.f;
    #pragma unroll
    for (int mk = 8; mk; mk >>= 1) x += __shfl_xor(x, mk);
    if (t == 0) red[0] = x;
  }
  __syncthreads();
  float r = red[0];
  __syncthreads();
  return r;
}

// moeTr layout: [ht=16][ks=7][bp=8][sr=4][hc=16] bf16 (see r4 notes).
#define WGSTR 232
#define CBSTR 260
#define CLSTR 252

__global__ __launch_bounds__(1024) void phaseC_kernel(
    const int* __restrict__ iseq, const float* __restrict__ w_in,
    const ushortT* __restrict__ moeB, const float* __restrict__ idxf,
    const float* __restrict__ graw,
    float* __restrict__ cap_out,    // OUT0
    float* __restrict__ mask_out,   // OUT2
    float* __restrict__ aidx_out)   // OUT4
{
  __shared__ ushortT moeTr[57344];
  __shared__ ushortT wgtT[16*WGSTR];
  __shared__ ushortT capB[16*CBSTR];
  __shared__ float bij[4032];
  __shared__ float n2p[16*17];
  __shared__ float n2s[16];
  __shared__ float tmaL[S_];
  __shared__ float red[16];
  __shared__ float maskf[A_];
  __shared__ int counts[A_], maxpos[A_];
  __shared__ int idxl[S_];
  __shared__ int padl[S_];

  const int t = threadIdx.x;
  const int b = blockIdx.x;
  const int base = b * S_;
  const int lane = t & 63, w = t >> 6;
  const int la = lane & 15, lg = lane >> 4;

  #pragma unroll
  for (int u = 0; u < 4; ++u) {
    int e = t + 1024*u;
    if (e < 3584) {
      int ht = e & 15, s = e >> 4;
      int ks = s >> 5, s4l = (s >> 2) & 7, sr = s & 3;
      int bp = (s4l & 1) ? 4 + (s4l >> 1) : (s4l >> 1);
      int li = ((ht*7 + ks)*8 + bp)*64 + sr*16;
      if (s < S_) {
        const ushortT* gp = &moeB[((size_t)(base + s))*H_ + ht*16];
        *(uint4*)&moeTr[li]     = *(const uint4*)gp;
        *(uint4*)&moeTr[li + 8] = *(const uint4*)(gp + 8);
      } else {
        uint4 z = {0,0,0,0};
        *(uint4*)&moeTr[li] = z; *(uint4*)&moeTr[li + 8] = z;
      }
    }
  }
  if (t < 512) {
    int a = t >> 5, s = 200 + (t & 31);
    wgtT[a*WGSTR + s] = 0;
  }

  if (t < A_) { counts[t] = 0; maxpos[t] = -1; }
  float wv = -3.0e38f;
  if (t < S_) {
    int s = t;
    padl[s] = (iseq[base+s] == 0) ? 1 : 0;
    idxl[s] = (int)idxf[base+s];
    wv = w_in[base+s];
    #pragma unroll
    for (int q = 0; q < 4; ++q)
      *(float4*)&bij[s*20 + 4*q] = *(const float4*)&graw[(base+s)*A_ + 4*q];
  }
  __syncthreads();

  if (t < S_ && !padl[t]) {
    atomicAdd(&counts[idxl[t]], 1);
    atomicMax(&maxpos[idxl[t]], t + 1);
  }
  float mxw = blk_max(wv, red);
  float ev = (t < S_) ? expf(wv - mxw) : 0.f;
  float sw = blk_sum(ev, red);
  if (t < S_) tmaL[t] = ev / sw;
  __syncthreads();
  if (t < A_) {
    int c = counts[t];
    float mkv = (c == 0) ? 1.f : 0.f;
    maskf[t] = mkv;
    mask_out[b*A_ + t] = mkv;
    int mp = maxpos[t];
    aidx_out[b*A_ + t] = (mp > 0) ? (float)(mp - 1) : -1.f;
  }
  __syncthreads();

  for (int iter = 0; iter < 3; ++iter) {
    if (t < S_) {
      int s = t;
      float row[16]; float mx = -3.0e38f;
      #pragma unroll
      for (int a = 0; a < 16; ++a) {
        float v = bij[s*20+a];
        v = (maskf[a] > 0.5f) ? NEGV : v;
        row[a] = v; mx = fmaxf(mx, v);
      }
      float sm = 0.f;
      #pragma unroll
      for (int a = 0; a < 16; ++a) { row[a] = expf(row[a] - mx); sm += row[a]; }
      float sc = (padl[s] ? 0.f : tmaL[s]) / sm;
      #pragma unroll
      for (int a = 0; a < 16; ++a) wgtT[a*WGSTR + s] = bf16u(row[a]*sc);
    }
    __syncthreads();

    f32x4 acc = (f32x4){0.f,0.f,0.f,0.f};
    {
      unsigned vA = (unsigned)(w*7168 + lane*8);
      #pragma unroll
      for (int ks = 0; ks < 7; ++ks) {
        unsigned vAk = vA + (unsigned)(ks*1024);
        long long r0, r1;
        asm volatile(
          "ds_read_b64_tr_b16 %0, %2\n\t"
          "ds_read_b64_tr_b16 %1, %2 offset:512\n\t"
          "s_waitcnt lgkmcnt(0)"
          : "=&v"(r0), "=&v"(r1) : "v"(vAk) : "memory");
        __builtin_amdgcn_sched_barrier(0);
        union { short8 v; long long q[2]; } uu;
        uu.q[0] = r0; uu.q[1] = r1;
        short8 bf = *(const short8*)&wgtT[la*WGSTR + ks*32 + lg*8];
        acc = __builtin_amdgcn_mfma_f32_16x16x32_bf16(uu.v, bf, acc, 0, 0, 0);
      }
    }
    {
      float n2 = acc[0]*acc[0] + acc[1]*acc[1] + acc[2]*acc[2] + acc[3]*acc[3];
      n2 += __shfl_xor(n2, 16);
      n2 += __shfl_xor(n2, 32);
      if (lane < 16) n2p[w*17 + lane] = n2;
    }
    __syncthreads();
    if (t < 16) {
      float sv = 0.f;
      #pragma unroll
      for (int w2 = 0; w2 < 16; ++w2) sv += n2p[w2*17 + t];
      n2s[t] = sv / (1.f + sv) / sqrtf(sv + 1e-9f);
    }
    __syncthreads();
    {
      float sc = n2s[la];
      if (iter < 2) {
        #pragma unroll
        for (int r = 0; r < 4; ++r)
          capB[la*CBSTR + w*16 + lg*4 + r] = bf16u(acc[r]*sc);
      } else {
        float* capl = bij;
        #pragma unroll
        for (int r = 0; r < 4; ++r)
          capl[la*CLSTR + w*16 + lg*4 + r] = acc[r]*sc;
      }
    }
    __syncthreads();

    if (iter < 2) {
      if (w < 13) {
        int sR = w*16 + la;
        int ksS = sR >> 5, s4l = (sR >> 2) & 7, sr = sR & 3;
        int bp = (s4l & 1) ? 4 + (s4l >> 1) : (s4l >> 1);
        int laneA = ksS*512 + bp*64 + sr*16 + (lg & 1)*8 + (lg >> 1)*3584;
        f32x4 accS = (f32x4){0.f,0.f,0.f,0.f};
        #pragma unroll
        for (int k4 = 0; k4 < 8; ++k4) {
          short8 am = *(const short8*)&moeTr[laneA + k4*7168];
          short8 bc = *(const short8*)&capB[la*CBSTR + k4*32 + lg*8];
          accS = __builtin_amdgcn_mfma_f32_16x16x32_bf16(am, bc, accS, 0, 0, 0);
        }
        int sW = w*16 + lg*4;
        #pragma unroll
        for (int r = 0; r < 4; ++r)
          if (sW + r < S_) bij[(sW + r)*20 + la] += accS[r];
      }
      __syncthreads();
    }
  }

  // final cap write (float4)
  {
    const float* capl = bij;
    int a = t >> 6, h4 = t & 63;
    float4 v = *(const float4*)&capl[a*CLSTR + 4*h4];
    *(float4*)&cap_out[((size_t)b*A_ + a)*H_ + 4*h4] = v;
  }
}

// ---------------- gather: activated[b,s,:] = cap[b, idx[b,s], :] ----------------
__global__ __launch_bounds__(256) void gather_kernel(
    const float* __restrict__ capv, const float* __restrict__ idxf,
    float* __restrict__ act)
{
  int e4 = blockIdx.x * 256 + threadIdx.x;   // 819200 float4s
  int m = e4 >> 6, h4 = e4 & 63;
  int b = m / S_;
  int id = (int)idxf[m];
  float4 v = *(const float4*)&capv[((b*A_) + id)*H_ + 4*h4];
  *(float4*)&act[(size_t)4*e4] = v;
}

extern "C" void kernel_launch(void* const* d_in, const int* in_sizes, int n_in,
                              void* d_out, int out_size, void* d_ws, size_t ws_size,
                              hipStream_t stream) {
  (void)in_sizes; (void)n_in; (void)out_size; (void)ws_size;
  const float* item  = (const float*)d_in[0];
  const int*   iseq  = (const int*)d_in[1];
  const int*   tseq  = (const int*)d_in[2];
  const float* W_lin = (const float*)d_in[3];
  const float* b_lin = (const float*)d_in[4];
  const float* asp   = (const float*)d_in[5];
  const float* pos   = (const float*)d_in[6];
  const float* tdt   = (const float*)d_in[7];
  const float* tdn   = (const float*)d_in[8];
  const float* Wa1   = (const float*)d_in[9];
  const float* ba1   = (const float*)d_in[10];
  const float* Wa2   = (const float*)d_in[11];
  const float* ba2   = (const float*)d_in[12];
  const float* g_ln  = (const float*)d_in[13];
  const float* b_ln  = (const float*)d_in[14];

  float* out    = (float*)d_out;
  float* cap_o  = out;                 // B*A*H     = 262144
  float* gate_o = out + 262144;        // B*S*A     = 204800
  float* mask_o = out + 466944;        // B*A       = 1024
  float* act_o  = out + 467968;        // B*S*H     = 3276800
  float* aidx_o = out + 3744768;       // B*A       = 1024
  float* idx_o  = out + 3745792;       // B*S       = 12800

  // ws: moeB bf16 (6.55MB) | Wa1T | WlinT | w f32 | graw f32
  ushortT* moeB  = (ushortT*)d_ws;
  ushortT* Wa1T  = (ushortT*)((char*)d_ws + 6553600);
  ushortT* WlinT = (ushortT*)((char*)d_ws + 6553600 + 131072);
  float*   w_ws  = (float*)((char*)d_ws + 6553600 + 262144);
  float*   graw  = (float*)((char*)d_ws + 6553600 + 262144 + 51200);

  prep_kernel<<<832, 256, 0, stream>>>(item, Wa1, W_lin, asp,
      Wa1T, WlinT, graw, gate_o, idx_o);
  gemm_kernel<<<200, 512, 0, stream>>>(item, iseq, tseq, pos, tdt, tdn,
      Wa1T, WlinT, ba1, Wa2, ba2, b_lin, g_ln, b_ln, w_ws, moeB);
  phaseC_kernel<<<B_, 1024, 0, stream>>>(iseq, w_ws, moeB, idx_o, graw,
      cap_o, mask_o, aidx_o);
  gather_kernel<<<(M_*H_/4)/256, 256, 0, stream>>>(cap_o, idx_o, act_o);
}